// Round 4
// baseline (387.767 us; speedup 1.0000x reference)
//
#include <hip/hip_runtime.h>

// Problem constants
#define BATCH 2
#define PLANES 3
#define CP 32
#define HH 256
#define WW 256
#define HWSZ 65536
#define HID 64
#define NOUT 33
#define NPTS_TOTAL 1048576
#define PLANE_ELEMS 2097152      // HWSZ*CP (u16 elems per plane, non-dup layout)
#define PLANE_ELEMS_DUP 4194304  // HWSZ*CP*2 (u16 elems per plane, dup-pair layout)
#define MPTS 128                 // points per fused block
#define GW_ELEMS 9216            // 2048 (W0t) + 4096 (W1t) + 3072 (W2t) bf16

typedef unsigned int u32;
typedef unsigned short u16;
typedef float floatx4 __attribute__((ext_vector_type(4)));
typedef short bf16x8 __attribute__((ext_vector_type(8)));

static __device__ __forceinline__ u16 f2bf(float f) {
    u32 u = __float_as_uint(f);
    return (u16)((u + 0x7fffu + ((u >> 16) & 1u)) >> 16);  // RNE
}
static __device__ __forceinline__ float bflo(u32 u) { return __uint_as_float(u << 16); }
static __device__ __forceinline__ float bfhi(u32 u) { return __uint_as_float(u & 0xffff0000u); }

// ---------------------------------------------------------------------------
// Kernel 1: transpose triplane (B,96,H,W) fp32 -> dup-pair layout
// (B*3, H, W, 32ch, 2) bf16: each 128-B pixel-block holds (v[x], v[x+1]) per
// channel -> any bilinear x-pair is ONE fully-utilized cache line.
// Block x=255 bakes in v1=0 (x+1 OOB).
// ---------------------------------------------------------------------------
__global__ __launch_bounds__(256) void transpose_dup_k(const float* __restrict__ tp,
                                                       u16* __restrict__ out) {
    int idx = blockIdx.x * 256 + threadIdx.x;  // < 6*65536
    int bp = idx >> 16;
    int yx = idx & 65535;
    int x = yx & 255;
    int b = bp / 3, p = bp - 3 * b;
    const float* src = tp + (((size_t)(b * 96 + p * 32)) << 16) + yx;
    const bool hasx1 = (x < 255);
    u16 v0[32], v1[32];
#pragma unroll
    for (int c = 0; c < 32; ++c) {
        v0[c] = f2bf(src[(size_t)c << 16]);
        v1[c] = hasx1 ? f2bf(src[((size_t)c << 16) + 1]) : (u16)0;
    }
    uint4* dst = (uint4*)(out + ((size_t)idx << 6));  // 64 u16 = 128 B per block
#pragma unroll
    for (int i = 0; i < 8; ++i) {
        uint4 w;
        w.x = (u32)v0[4 * i + 0] | ((u32)v1[4 * i + 0] << 16);
        w.y = (u32)v0[4 * i + 1] | ((u32)v1[4 * i + 1] << 16);
        w.z = (u32)v0[4 * i + 2] | ((u32)v1[4 * i + 2] << 16);
        w.w = (u32)v0[4 * i + 3] | ((u32)v1[4 * i + 3] << 16);
        dst[i] = w;
    }
}

// ---------------------------------------------------------------------------
// Kernel 1b: pre-tile MLP weights into fragment-major bf16 blob (once).
// gW[0..2048)      = W0t[m][k] (m<64,k<32):  gW[m*32+k]        = W0[k*64+m]
// gW[2048..6144)   = W1t[m][k] (64x64):      gW[2048+m*64+k]   = W1[k*64+m]
// gW[6144..9216)   = W2t[m][k] (m<48,k<64):  gW[6144+m*64+k]   = W2[k*33+m] (m<33) else 0
// ---------------------------------------------------------------------------
__global__ __launch_bounds__(256) void prep_w_k(const float* __restrict__ W0,
                                                const float* __restrict__ W1,
                                                const float* __restrict__ W2,
                                                u16* __restrict__ gW) {
    int i = blockIdx.x * 256 + threadIdx.x;  // < GW_ELEMS
    if (i < 2048) {
        int m = i >> 5, k = i & 31;
        gW[i] = f2bf(W0[k * 64 + m]);
    } else if (i < 6144) {
        int j = i - 2048;
        int m = j >> 6, k = j & 63;
        gW[i] = f2bf(W1[k * 64 + m]);
    } else {
        int j = i - 6144;
        int m = j >> 6, k = j & 63;
        gW[i] = (m < NOUT) ? f2bf(W2[k * NOUT + m]) : (u16)0;
    }
}

// ---------------------------------------------------------------------------
// Kernel 2: fused gather + MFMA MLP, v3 (single X LDS buffer -> 8 blocks/CU).
//  - Weights: direct global->register A-frag loads from gW (L1 broadcast).
//  - X0: register handoff (thread (wv,lane,it) gathers exactly its layer-0
//    B-fragment: pt = wv*32+it*16+(lane&15), channel octet q = lane>>4).
//  - LDS: ONE buffer sX (128*72 u16 = 18.4 KB) time-shared X1 -> X2 -> sOut,
//    with barriers separating read and overwrite phases. 8 blocks/CU.
//  - __launch_bounds__(256,8): VGPR cap 64 (compiler used 56 uncapped -> safe).
// MFMA semantics (verified): D[m][n] = sum_k Wt[m][k]*X[n][k],
// A[m=lane&15][k=qd*8+j], B[k=qd*8+j][n=lane&15], D: col=lane&15(n),
// row=qd*4+r(m). Padded LDS stride 72 keeps b128 reads conflict-free.
// ---------------------------------------------------------------------------
__global__ __launch_bounds__(256, 8) void fused4_k(const u16* __restrict__ planes,
                                                   const u16* __restrict__ gW,
                                                   const float* __restrict__ points,
                                                   const float* __restrict__ b0,
                                                   const float* __restrict__ b1,
                                                   const float* __restrict__ b2,
                                                   float* __restrict__ out) {
    __shared__ __align__(16) u16 sX[MPTS * 72];   // X1, then X2, then sOut (f32 stride 36)

    const int tid = threadIdx.x;
    const int lane = tid & 63, wv = tid >> 6;
    const int ln = lane & 15, qd = lane >> 4;
    const size_t pbase = (size_t)blockIdx.x * MPTS;
    const int bBatch = blockIdx.x >> 12;  // 4096 blocks per batch

    // ---- gather phase: produce layer-0 B-fragments directly in registers ----
    bf16x8 bfr[2];
#pragma unroll
    for (int it = 0; it < 2; ++it) {
        const int pt = wv * 32 + it * 16 + ln;
        const size_t gpt = pbase + pt;
        const float px = points[gpt * 3 + 0];
        const float py = points[gpt * 3 + 1];
        const float pz = points[gpt * 3 + 2];
        float acc[8];
#pragma unroll
        for (int j = 0; j < 8; ++j) acc[j] = 0.f;
#pragma unroll
        for (int p = 0; p < PLANES; ++p) {
            const float gx = (p == 2) ? py : px;
            const float gy = (p == 0) ? py : pz;
            const float x = (gx + 1.0f) * 128.0f - 0.5f;
            const float y = (gy + 1.0f) * 128.0f - 0.5f;
            const float xf = floorf(x), yf = floorf(y);
            const float wx = x - xf, wy = y - yf;
            const int ix0 = (int)xf, iy0 = (int)yf;          // in [-1,255]
            const int xb = max(ix0, 0);
            const float wA0 = (ix0 >= 0) ? (1.f - wx) : wx;  // x0=-1: wx*v[0] via lo half
            const float wB0 = (ix0 >= 0) ? wx : 0.f;
            const u16* pb = planes + ((size_t)(bBatch * 3 + p) << 22);
#pragma unroll
            for (int r = 0; r < 2; ++r) {
                const int iy = iy0 + r;
                const bool vy = (iy >= 0) & (iy < HH);
                const float wrow = (r ? wy : (1.f - wy));
                const float wa = vy ? wrow * wA0 : 0.f;
                const float wb = vy ? wrow * wB0 : 0.f;
                const int iyc = min(max(iy, 0), HH - 1);
                const u16* src = pb + (((size_t)((iyc << 8) | xb)) << 6) + (qd << 4);
                const uint4 d0 = *(const uint4*)src;        // ch qd*8+0..3 (lo/hi = x0/x1)
                const uint4 d1 = *(const uint4*)(src + 8);  // ch qd*8+4..7
#pragma unroll
                for (int j = 0; j < 4; ++j) {
                    const u32 u = (&d0.x)[j];
                    acc[j] = fmaf(wa, bflo(u), fmaf(wb, bfhi(u), acc[j]));
                    const u32 u2 = (&d1.x)[j];
                    acc[4 + j] = fmaf(wa, bflo(u2), fmaf(wb, bfhi(u2), acc[4 + j]));
                }
            }
        }
        u32 w[4];
#pragma unroll
        for (int j = 0; j < 4; ++j)
            w[j] = (u32)f2bf(acc[2 * j]) | ((u32)f2bf(acc[2 * j + 1]) << 16);
        bf16x8 v;
        ((u32*)&v)[0] = w[0]; ((u32*)&v)[1] = w[1];
        ((u32*)&v)[2] = w[2]; ((u32*)&v)[3] = w[3];
        bfr[it] = v;
    }

    // ---- layer 0: K=32, M=64 (4 tiles), B-frags already in registers ----
    floatx4 acc0[2][4];
    {
        bf16x8 a0[4];
#pragma unroll
        for (int mt = 0; mt < 4; ++mt)
            a0[mt] = *(const bf16x8*)(gW + (mt * 16 + ln) * 32 + qd * 8);
#pragma unroll
        for (int it = 0; it < 2; ++it)
#pragma unroll
            for (int mt = 0; mt < 4; ++mt) {
                floatx4 z = {0.f, 0.f, 0.f, 0.f};
                acc0[it][mt] = __builtin_amdgcn_mfma_f32_16x16x32_bf16(a0[mt], bfr[it], z, 0, 0, 0);
            }
    }
    // epilogue 0 -> X1 (sX, stride 72); rows wave-private
    {
        float4 bias0[4];
#pragma unroll
        for (int mt = 0; mt < 4; ++mt) bias0[mt] = *(const float4*)(b0 + mt * 16 + qd * 4);
#pragma unroll
        for (int it = 0; it < 2; ++it) {
            const int n = wv * 32 + it * 16 + ln;
#pragma unroll
            for (int mt = 0; mt < 4; ++mt) {
                u16 p[4];
#pragma unroll
                for (int r = 0; r < 4; ++r) {
                    float v = acc0[it][mt][r] + (&bias0[mt].x)[r];
                    v = (v >= 0.f) ? v : 0.01f * v;
                    p[r] = f2bf(v);
                }
                uint2 dd = make_uint2((u32)p[0] | ((u32)p[1] << 16), (u32)p[2] | ((u32)p[3] << 16));
                *(uint2*)(sX + n * 72 + mt * 16 + qd * 4) = dd;
            }
        }
    }
    __syncthreads();  // X1 complete

    // ---- layer 1: K=64 (2 chunks), reads X1 ----
    floatx4 acc1[2][4];
    {
        const u16* gW1 = gW + 2048;
        bf16x8 a1[4][2];
#pragma unroll
        for (int mt = 0; mt < 4; ++mt)
#pragma unroll
            for (int c = 0; c < 2; ++c)
                a1[mt][c] = *(const bf16x8*)(gW1 + (mt * 16 + ln) * 64 + c * 32 + qd * 8);
#pragma unroll
        for (int it = 0; it < 2; ++it) {
            const int n = wv * 32 + it * 16 + ln;
            bf16x8 f0 = *(const bf16x8*)(sX + n * 72 + qd * 8);
            bf16x8 f1 = *(const bf16x8*)(sX + n * 72 + 32 + qd * 8);
#pragma unroll
            for (int mt = 0; mt < 4; ++mt) {
                floatx4 z = {0.f, 0.f, 0.f, 0.f};
                floatx4 t = __builtin_amdgcn_mfma_f32_16x16x32_bf16(a1[mt][0], f0, z, 0, 0, 0);
                acc1[it][mt] = __builtin_amdgcn_mfma_f32_16x16x32_bf16(a1[mt][1], f1, t, 0, 0, 0);
            }
        }
    }
    __syncthreads();  // all waves' X1 reads done; sX may be overwritten

    // epilogue 1 -> X2 (sX, stride 72)
    {
        float4 bias1[4];
#pragma unroll
        for (int mt = 0; mt < 4; ++mt) bias1[mt] = *(const float4*)(b1 + mt * 16 + qd * 4);
#pragma unroll
        for (int it = 0; it < 2; ++it) {
            const int n = wv * 32 + it * 16 + ln;
#pragma unroll
            for (int mt = 0; mt < 4; ++mt) {
                u16 p[4];
#pragma unroll
                for (int r = 0; r < 4; ++r) {
                    float v = acc1[it][mt][r] + (&bias1[mt].x)[r];
                    v = (v >= 0.f) ? v : 0.01f * v;
                    p[r] = f2bf(v);
                }
                uint2 dd = make_uint2((u32)p[0] | ((u32)p[1] << 16), (u32)p[2] | ((u32)p[3] << 16));
                *(uint2*)(sX + n * 72 + mt * 16 + qd * 4) = dd;
            }
        }
    }
    __syncthreads();  // X2 complete

    // ---- layer 2: K=64, M=48 (3 tiles; m<33 valid), reads X2 ----
    floatx4 acc2[2][3];
    {
        const u16* gW2 = gW + 6144;
        bf16x8 a2[3][2];
#pragma unroll
        for (int mt = 0; mt < 3; ++mt)
#pragma unroll
            for (int c = 0; c < 2; ++c)
                a2[mt][c] = *(const bf16x8*)(gW2 + (mt * 16 + ln) * 64 + c * 32 + qd * 8);
#pragma unroll
        for (int it = 0; it < 2; ++it) {
            const int n = wv * 32 + it * 16 + ln;
            bf16x8 f0 = *(const bf16x8*)(sX + n * 72 + qd * 8);
            bf16x8 f1 = *(const bf16x8*)(sX + n * 72 + 32 + qd * 8);
#pragma unroll
            for (int mt = 0; mt < 3; ++mt) {
                floatx4 z = {0.f, 0.f, 0.f, 0.f};
                floatx4 t = __builtin_amdgcn_mfma_f32_16x16x32_bf16(a2[mt][0], f0, z, 0, 0, 0);
                acc2[it][mt] = __builtin_amdgcn_mfma_f32_16x16x32_bf16(a2[mt][1], f1, t, 0, 0, 0);
            }
        }
    }
    __syncthreads();  // all waves' X2 reads done; sX may be overwritten

    // epilogue 2 -> sOut fp32 stride 36 (overlays sX); rows wave-private
    float* sOut = (float*)sX;
#pragma unroll
    for (int it = 0; it < 2; ++it) {
        const int n = wv * 32 + it * 16 + ln;
#pragma unroll
        for (int mt = 0; mt < 3; ++mt)
#pragma unroll
            for (int r = 0; r < 4; ++r) {
                const int m = mt * 16 + qd * 4 + r;
                if (m < NOUT) sOut[n * 36 + m] = acc2[it][mt][r] + b2[m];
            }
    }
    __syncthreads();

    // coalesced copy out: MPTS*33 floats
    float* og = out + pbase * NOUT;
    for (int i = tid; i < MPTS * NOUT; i += 256) {
        int n = i / 33, m = i - 33 * n;
        og[i] = sOut[n * 36 + m];
    }
}

// ---------------------------------------------------------------------------
// Fallback: round-1 fused kernel (ws >= dup planes only). 210 us measured.
// ---------------------------------------------------------------------------
__global__ __launch_bounds__(256, 2) void fused_mfma_k(const u16* __restrict__ planes,
                                                       const float* __restrict__ points,
                                                       const float* __restrict__ W0,
                                                       const float* __restrict__ b0,
                                                       const float* __restrict__ W1,
                                                       const float* __restrict__ b1,
                                                       const float* __restrict__ W2,
                                                       const float* __restrict__ b2,
                                                       float* __restrict__ out) {
    __shared__ __align__(16) u16 sW0t[64 * 40];
    __shared__ __align__(16) u16 sW1t[64 * 72];
    __shared__ __align__(16) u16 sW2t[48 * 72];
    __shared__ __align__(16) u16 sR0[MPTS * 72];
    __shared__ __align__(16) u16 sR1[MPTS * 72];
    __shared__ float sB0[64], sB1[64], sB2[33];

    const int tid = threadIdx.x;
    for (int i = tid; i < 32 * 64; i += 256) { int k = i >> 6, m = i & 63; sW0t[m * 40 + k] = f2bf(W0[i]); }
    for (int i = tid; i < 64 * 64; i += 256) { int k = i >> 6, m = i & 63; sW1t[m * 72 + k] = f2bf(W1[i]); }
    for (int i = tid; i < 64 * 33; i += 256) { int k = i / 33, m = i - 33 * k; sW2t[m * 72 + k] = f2bf(W2[i]); }
    if (tid < 64) { sB0[tid] = b0[tid]; sB1[tid] = b1[tid]; }
    if (tid < 33) sB2[tid] = b2[tid];

    const size_t pbase = (size_t)blockIdx.x * MPTS;
    float* sPts = (float*)sR1;  // overlay; dead before epilogue 0
    for (int i = tid; i < MPTS * 3; i += 256) sPts[i] = points[pbase * 3 + i];
    __syncthreads();

    const int bBatch = blockIdx.x >> 12;
#pragma unroll
    for (int t = 0; t < 2; ++t) {
        const int task = t * 256 + tid;
        const int pt = task >> 2, q = task & 3;
        const float px = sPts[pt * 3 + 0];
        const float py = sPts[pt * 3 + 1];
        const float pz = sPts[pt * 3 + 2];
        float acc[8];
#pragma unroll
        for (int j = 0; j < 8; ++j) acc[j] = 0.f;
#pragma unroll
        for (int p = 0; p < PLANES; ++p) {
            const float gx = (p == 2) ? py : px;
            const float gy = (p == 0) ? py : pz;
            const float x = (gx + 1.0f) * 128.0f - 0.5f;
            const float y = (gy + 1.0f) * 128.0f - 0.5f;
            const float xf = floorf(x), yf = floorf(y);
            const float wx = x - xf, wy = y - yf;
            const int ix0 = (int)xf, iy0 = (int)yf;
            const int xb = max(ix0, 0);
            const float ax = (ix0 >= 0) ? (1.f - wx) : wx;
            const float bx = (ix0 >= 0) ? wx : 0.f;
            const u16* pb = planes + ((size_t)(bBatch * 3 + p) << 22);
#pragma unroll
            for (int r = 0; r < 2; ++r) {
                const int iy = iy0 + r;
                const bool vy = (iy >= 0) & (iy < HH);
                const float wrow = (r ? wy : (1.f - wy));
                const float wa = vy ? wrow * ax : 0.f;
                const float wb = vy ? wrow * bx : 0.f;
                const int iyc = min(max(iy, 0), HH - 1);
                const u16* src = pb + (((size_t)((iyc << 8) | xb)) << 6) + (q << 4);
                const uint4 d0 = *(const uint4*)src;
                const uint4 d1 = *(const uint4*)(src + 8);
#pragma unroll
                for (int j = 0; j < 4; ++j) {
                    const u32 u = (&d0.x)[j];
                    acc[j] = fmaf(wa, bflo(u), fmaf(wb, bfhi(u), acc[j]));
                    const u32 u2 = (&d1.x)[j];
                    acc[4 + j] = fmaf(wa, bflo(u2), fmaf(wb, bfhi(u2), acc[4 + j]));
                }
            }
        }
        uint4 o;
        o.x = (u32)f2bf(acc[0]) | ((u32)f2bf(acc[1]) << 16);
        o.y = (u32)f2bf(acc[2]) | ((u32)f2bf(acc[3]) << 16);
        o.z = (u32)f2bf(acc[4]) | ((u32)f2bf(acc[5]) << 16);
        o.w = (u32)f2bf(acc[6]) | ((u32)f2bf(acc[7]) << 16);
        *(uint4*)(sR0 + pt * 40 + q * 8) = o;
    }
    __syncthreads();

    const int lane = tid & 63, wv = tid >> 6;
    const int ln = lane & 15, qd = lane >> 4;

    bf16x8 a0[4];
#pragma unroll
    for (int mt = 0; mt < 4; ++mt)
        a0[mt] = *(const bf16x8*)(sW0t + (mt * 16 + ln) * 40 + qd * 8);
    bf16x8 bx0[2];
#pragma unroll
    for (int nt = 0; nt < 2; ++nt)
        bx0[nt] = *(const bf16x8*)(sR0 + (wv * 32 + nt * 16 + ln) * 40 + qd * 8);
    floatx4 acc0[2][4];
#pragma unroll
    for (int nt = 0; nt < 2; ++nt)
#pragma unroll
        for (int mt = 0; mt < 4; ++mt) {
            floatx4 z = {0.f, 0.f, 0.f, 0.f};
            acc0[nt][mt] = __builtin_amdgcn_mfma_f32_16x16x32_bf16(a0[mt], bx0[nt], z, 0, 0, 0);
        }
#pragma unroll
    for (int nt = 0; nt < 2; ++nt) {
        const int n = wv * 32 + nt * 16 + ln;
#pragma unroll
        for (int mt = 0; mt < 4; ++mt) {
            u16 p[4];
#pragma unroll
            for (int r = 0; r < 4; ++r) {
                const int m = mt * 16 + qd * 4 + r;
                float v = acc0[nt][mt][r] + sB0[m];
                v = (v >= 0.f) ? v : 0.01f * v;
                p[r] = f2bf(v);
            }
            uint2 dd = make_uint2((u32)p[0] | ((u32)p[1] << 16), (u32)p[2] | ((u32)p[3] << 16));
            *(uint2*)(sR1 + n * 72 + mt * 16 + qd * 4) = dd;
        }
    }

    bf16x8 a1[4][2];
#pragma unroll
    for (int mt = 0; mt < 4; ++mt)
#pragma unroll
        for (int c = 0; c < 2; ++c)
            a1[mt][c] = *(const bf16x8*)(sW1t + (mt * 16 + ln) * 72 + c * 32 + qd * 8);
    floatx4 acc1[2][4];
#pragma unroll
    for (int nt = 0; nt < 2; ++nt) {
        const int n = wv * 32 + nt * 16 + ln;
        bf16x8 bf0 = *(const bf16x8*)(sR1 + n * 72 + qd * 8);
        bf16x8 bf1 = *(const bf16x8*)(sR1 + n * 72 + 32 + qd * 8);
#pragma unroll
        for (int mt = 0; mt < 4; ++mt) {
            floatx4 z = {0.f, 0.f, 0.f, 0.f};
            floatx4 t = __builtin_amdgcn_mfma_f32_16x16x32_bf16(a1[mt][0], bf0, z, 0, 0, 0);
            acc1[nt][mt] = __builtin_amdgcn_mfma_f32_16x16x32_bf16(a1[mt][1], bf1, t, 0, 0, 0);
        }
    }
    __syncthreads();

#pragma unroll
    for (int nt = 0; nt < 2; ++nt) {
        const int n = wv * 32 + nt * 16 + ln;
#pragma unroll
        for (int mt = 0; mt < 4; ++mt) {
            u16 p[4];
#pragma unroll
            for (int r = 0; r < 4; ++r) {
                const int m = mt * 16 + qd * 4 + r;
                float v = acc1[nt][mt][r] + sB1[m];
                v = (v >= 0.f) ? v : 0.01f * v;
                p[r] = f2bf(v);
            }
            uint2 dd = make_uint2((u32)p[0] | ((u32)p[1] << 16), (u32)p[2] | ((u32)p[3] << 16));
            *(uint2*)(sR0 + n * 72 + mt * 16 + qd * 4) = dd;
        }
    }

    bf16x8 a2[3][2];
#pragma unroll
    for (int mt = 0; mt < 3; ++mt)
#pragma unroll
        for (int c = 0; c < 2; ++c)
            a2[mt][c] = *(const bf16x8*)(sW2t + (mt * 16 + ln) * 72 + c * 32 + qd * 8);
    floatx4 acc2[2][3];
#pragma unroll
    for (int nt = 0; nt < 2; ++nt) {
        const int n = wv * 32 + nt * 16 + ln;
        bf16x8 bf0 = *(const bf16x8*)(sR0 + n * 72 + qd * 8);
        bf16x8 bf1 = *(const bf16x8*)(sR0 + n * 72 + 32 + qd * 8);
#pragma unroll
        for (int mt = 0; mt < 3; ++mt) {
            floatx4 z = {0.f, 0.f, 0.f, 0.f};
            floatx4 t = __builtin_amdgcn_mfma_f32_16x16x32_bf16(a2[mt][0], bf0, z, 0, 0, 0);
            acc2[nt][mt] = __builtin_amdgcn_mfma_f32_16x16x32_bf16(a2[mt][1], bf1, t, 0, 0, 0);
        }
    }
    __syncthreads();

    float* sOut = (float*)sR1;
#pragma unroll
    for (int nt = 0; nt < 2; ++nt) {
        const int n = wv * 32 + nt * 16 + ln;
#pragma unroll
        for (int mt = 0; mt < 3; ++mt)
#pragma unroll
            for (int r = 0; r < 4; ++r) {
                const int m = mt * 16 + qd * 4 + r;
                if (m < NOUT) sOut[n * 36 + m] = acc2[nt][mt][r] + sB2[m];
            }
    }
    __syncthreads();

    float* og = out + pbase * NOUT;
    for (int i = tid; i < MPTS * NOUT; i += 256) {
        int n = i / 33, m = i - 33 * n;
        og[i] = sOut[n * 36 + m];
    }
}

// ---------------------------------------------------------------------------
// Fallback: fully scalar, no workspace.
// ---------------------------------------------------------------------------
__global__ __launch_bounds__(256) void fused_fallback_k(const float* __restrict__ planes,
                                                        const float* __restrict__ points,
                                                        const float* __restrict__ W0,
                                                        const float* __restrict__ b0,
                                                        const float* __restrict__ W1,
                                                        const float* __restrict__ b1,
                                                        const float* __restrict__ W2,
                                                        const float* __restrict__ b2,
                                                        float* __restrict__ out) {
    const int tid = threadIdx.x;
    const int pgl = blockIdx.x * 256 + tid;
    const int b = pgl >> 19;
    const float px = points[(size_t)pgl * 3 + 0];
    const float py = points[(size_t)pgl * 3 + 1];
    const float pz = points[(size_t)pgl * 3 + 2];
    float feat[CP];
#pragma unroll
    for (int c = 0; c < CP; ++c) feat[c] = 0.f;
#pragma unroll
    for (int p = 0; p < PLANES; ++p) {
        const float gx = (p == 2) ? py : px;
        const float gy = (p == 0) ? py : pz;
        const float x = (gx + 1.0f) * 128.0f - 0.5f;
        const float y = (gy + 1.0f) * 128.0f - 0.5f;
        const float xf = floorf(x), yf = floorf(y);
        const float wx = x - xf, wy = y - yf;
        const int ix0 = (int)xf, iy0 = (int)yf;
        const float* pb = planes + (((size_t)(b * 96 + p * 32)) << 16);
        auto corner = [&](int ix, int iy, float w) {
            const bool v = (ix >= 0) & (ix < WW) & (iy >= 0) & (iy < HH);
            w = v ? w : 0.f;
            const int ixc = min(max(ix, 0), WW - 1);
            const int iyc = min(max(iy, 0), HH - 1);
            const int yx = (iyc << 8) | ixc;
            const float* src = pb + yx;
#pragma unroll
            for (int c = 0; c < CP; ++c) feat[c] = fmaf(w, src[(size_t)c << 16], feat[c]);
        };
        corner(ix0,     iy0,     (1.f - wx) * (1.f - wy));
        corner(ix0 + 1, iy0,     wx * (1.f - wy));
        corner(ix0,     iy0 + 1, (1.f - wx) * wy);
        corner(ix0 + 1, iy0 + 1, wx * wy);
    }
    float h0[HID];
#pragma unroll
    for (int j = 0; j < HID; ++j) h0[j] = b0[j];
    for (int k = 0; k < CP; ++k) {
        const float f = feat[k];
#pragma unroll
        for (int j = 0; j < HID; ++j) h0[j] = fmaf(f, W0[k * HID + j], h0[j]);
    }
#pragma unroll
    for (int j = 0; j < HID; ++j) h0[j] = (h0[j] >= 0.f) ? h0[j] : 0.01f * h0[j];
    float h1[HID];
#pragma unroll
    for (int j = 0; j < HID; ++j) h1[j] = b1[j];
    for (int k = 0; k < HID; ++k) {
        const float f = h0[k];
#pragma unroll
        for (int j = 0; j < HID; ++j) h1[j] = fmaf(f, W1[k * HID + j], h1[j]);
    }
#pragma unroll
    for (int j = 0; j < HID; ++j) h1[j] = (h1[j] >= 0.f) ? h1[j] : 0.01f * h1[j];
    float o[NOUT];
#pragma unroll
    for (int j = 0; j < NOUT; ++j) o[j] = b2[j];
    for (int k = 0; k < HID; ++k) {
        const float f = h1[k];
#pragma unroll
        for (int j = 0; j < NOUT; ++j) o[j] = fmaf(f, W2[k * NOUT + j], o[j]);
    }
    float* op = out + (size_t)pgl * NOUT;
#pragma unroll
    for (int j = 0; j < NOUT; ++j) op[j] = o[j];
}

// ---------------------------------------------------------------------------
extern "C" void kernel_launch(void* const* d_in, const int* in_sizes, int n_in,
                              void* d_out, int out_size, void* d_ws, size_t ws_size,
                              hipStream_t stream) {
    const float* triplane = (const float*)d_in[0];
    const float* points   = (const float*)d_in[1];
    const float* W0 = (const float*)d_in[2];
    const float* b0 = (const float*)d_in[3];
    const float* W1 = (const float*)d_in[4];
    const float* b1 = (const float*)d_in[5];
    const float* W2 = (const float*)d_in[6];
    const float* b2 = (const float*)d_in[7];
    float* out = (float*)d_out;

    const size_t dupElems = (size_t)BATCH * PLANES * PLANE_ELEMS_DUP;
    const size_t needDup  = dupElems * sizeof(u16);                    // 50.3 MB
    const size_t needAll  = needDup + GW_ELEMS * sizeof(u16);          // + 18.4 KB

    if (d_ws != nullptr && ws_size >= needAll) {
        u16* planesW = (u16*)d_ws;
        u16* gW      = planesW + dupElems;
        transpose_dup_k<<<(BATCH * PLANES * HWSZ) / 256, 256, 0, stream>>>(triplane, planesW);
        prep_w_k<<<GW_ELEMS / 256, 256, 0, stream>>>(W0, W1, W2, gW);
        fused4_k<<<NPTS_TOTAL / MPTS, 256, 0, stream>>>(planesW, gW, points, b0, b1, b2, out);
    } else if (d_ws != nullptr && ws_size >= needDup) {
        u16* planesW = (u16*)d_ws;
        transpose_dup_k<<<(BATCH * PLANES * HWSZ) / 256, 256, 0, stream>>>(triplane, planesW);
        fused_mfma_k<<<NPTS_TOTAL / MPTS, 256, 0, stream>>>(planesW, points, W0, b0, W1, b1, W2, b2, out);
    } else {
        fused_fallback_k<<<NPTS_TOTAL / 256, 256, 0, stream>>>(
            triplane, points, W0, b0, W1, b1, W2, b2, out);
    }
}

// Round 5
// 374.354 us; speedup vs baseline: 1.0358x; 1.0358x over previous
//
#include <hip/hip_runtime.h>

// Problem constants
#define BATCH 2
#define PLANES 3
#define CP 32
#define HH 256
#define WW 256
#define HWSZ 65536
#define HID 64
#define NOUT 33
#define NPTS_TOTAL 1048576
#define PLANE_ELEMS 2097152      // HWSZ*CP (u16 elems per plane, non-dup layout)
#define PLANE_ELEMS_DUP 4194304  // HWSZ*CP*2 (u16 elems per plane, dup-pair layout)
#define MPTS 128                 // points per fused block
#define GW_ELEMS 9216            // 2048 (W0t) + 4096 (W1t) + 3072 (W2t) bf16

typedef unsigned int u32;
typedef unsigned short u16;
typedef float floatx4 __attribute__((ext_vector_type(4)));
typedef short bf16x8 __attribute__((ext_vector_type(8)));

static __device__ __forceinline__ u16 f2bf(float f) {
    u32 u = __float_as_uint(f);
    return (u16)((u + 0x7fffu + ((u >> 16) & 1u)) >> 16);  // RNE
}
static __device__ __forceinline__ float bflo(u32 u) { return __uint_as_float(u << 16); }
static __device__ __forceinline__ float bfhi(u32 u) { return __uint_as_float(u & 0xffff0000u); }

// ---------------------------------------------------------------------------
// Kernel 1: transpose triplane (B,96,H,W) fp32 -> dup-pair layout
// (B*3, H, W, 32ch, 2) bf16: each 128-B pixel-block holds (v[x], v[x+1]) per
// channel -> any bilinear x-pair is ONE fully-utilized cache line.
// Block x=255 bakes in v1=0 (x+1 OOB).
// ---------------------------------------------------------------------------
__global__ __launch_bounds__(256) void transpose_dup_k(const float* __restrict__ tp,
                                                       u16* __restrict__ out) {
    int idx = blockIdx.x * 256 + threadIdx.x;  // < 6*65536
    int bp = idx >> 16;
    int yx = idx & 65535;
    int x = yx & 255;
    int b = bp / 3, p = bp - 3 * b;
    const float* src = tp + (((size_t)(b * 96 + p * 32)) << 16) + yx;
    const bool hasx1 = (x < 255);
    u16 v0[32], v1[32];
#pragma unroll
    for (int c = 0; c < 32; ++c) {
        v0[c] = f2bf(src[(size_t)c << 16]);
        v1[c] = hasx1 ? f2bf(src[((size_t)c << 16) + 1]) : (u16)0;
    }
    uint4* dst = (uint4*)(out + ((size_t)idx << 6));  // 64 u16 = 128 B per block
#pragma unroll
    for (int i = 0; i < 8; ++i) {
        uint4 w;
        w.x = (u32)v0[4 * i + 0] | ((u32)v1[4 * i + 0] << 16);
        w.y = (u32)v0[4 * i + 1] | ((u32)v1[4 * i + 1] << 16);
        w.z = (u32)v0[4 * i + 2] | ((u32)v1[4 * i + 2] << 16);
        w.w = (u32)v0[4 * i + 3] | ((u32)v1[4 * i + 3] << 16);
        dst[i] = w;
    }
}

// ---------------------------------------------------------------------------
// Kernel 1b: pre-tile MLP weights into fragment-major bf16 blob (once).
// gW[0..2048)      = W0t[m][k] (m<64,k<32):  gW[m*32+k]        = W0[k*64+m]
// gW[2048..6144)   = W1t[m][k] (64x64):      gW[2048+m*64+k]   = W1[k*64+m]
// gW[6144..9216)   = W2t[m][k] (m<48,k<64):  gW[6144+m*64+k]   = W2[k*33+m] (m<33) else 0
// ---------------------------------------------------------------------------
__global__ __launch_bounds__(256) void prep_w_k(const float* __restrict__ W0,
                                                const float* __restrict__ W1,
                                                const float* __restrict__ W2,
                                                u16* __restrict__ gW) {
    int i = blockIdx.x * 256 + threadIdx.x;  // < GW_ELEMS
    if (i < 2048) {
        int m = i >> 5, k = i & 31;
        gW[i] = f2bf(W0[k * 64 + m]);
    } else if (i < 6144) {
        int j = i - 2048;
        int m = j >> 6, k = j & 63;
        gW[i] = f2bf(W1[k * 64 + m]);
    } else {
        int j = i - 6144;
        int m = j >> 6, k = j & 63;
        gW[i] = (m < NOUT) ? f2bf(W2[k * NOUT + m]) : (u16)0;
    }
}

// ---------------------------------------------------------------------------
// Kernel 2: fused gather + MFMA MLP, v4: register-liveness-trimmed so that
// __launch_bounds__(256,6) (unified VGPR+AGPR budget 85) holds WITHOUT spill.
//  - Layer 0: per-mt interleave (mfma -> bias/leaky/pack -> LDS write), one
//    floatx4 accumulator live at a time.
//  - Layer 1: weights streamed per-mt; acc packed to bf16 uint2 immediately;
//    only pk1[2][4] (16 regs) crosses the read/overwrite barrier.
//  - Layer 2: acc2[2][3] (24 regs) crosses its barrier (fits).
//  - LDS: ONE buffer sX (128*72 u16 = 18.4 KB) time-shared X1 -> X2 -> sOut.
// MFMA semantics (verified): D[m][n] = sum_k Wt[m][k]*X[n][k],
// A[m=lane&15][k=qd*8+j], B[k=qd*8+j][n=lane&15], D: col=lane&15(n),
// row=qd*4+r(m). Padded LDS stride 72 keeps b128 reads conflict-free.
// ---------------------------------------------------------------------------
__global__ __launch_bounds__(256, 6) void fused5_k(const u16* __restrict__ planes,
                                                   const u16* __restrict__ gW,
                                                   const float* __restrict__ points,
                                                   const float* __restrict__ b0,
                                                   const float* __restrict__ b1,
                                                   const float* __restrict__ b2,
                                                   float* __restrict__ out) {
    __shared__ __align__(16) u16 sX[MPTS * 72];   // X1, then X2, then sOut (f32 stride 36)

    const int tid = threadIdx.x;
    const int lane = tid & 63, wv = tid >> 6;
    const int ln = lane & 15, qd = lane >> 4;
    const size_t pbase = (size_t)blockIdx.x * MPTS;
    const int bBatch = blockIdx.x >> 12;  // 4096 blocks per batch

    // ---- gather phase: produce layer-0 B-fragments directly in registers ----
    bf16x8 bfr[2];
#pragma unroll
    for (int it = 0; it < 2; ++it) {
        const int pt = wv * 32 + it * 16 + ln;
        const size_t gpt = pbase + pt;
        const float px = points[gpt * 3 + 0];
        const float py = points[gpt * 3 + 1];
        const float pz = points[gpt * 3 + 2];
        float acc[8];
#pragma unroll
        for (int j = 0; j < 8; ++j) acc[j] = 0.f;
#pragma unroll
        for (int p = 0; p < PLANES; ++p) {
            const float gx = (p == 2) ? py : px;
            const float gy = (p == 0) ? py : pz;
            const float x = (gx + 1.0f) * 128.0f - 0.5f;
            const float y = (gy + 1.0f) * 128.0f - 0.5f;
            const float xf = floorf(x), yf = floorf(y);
            const float wx = x - xf, wy = y - yf;
            const int ix0 = (int)xf, iy0 = (int)yf;          // in [-1,255]
            const int xb = max(ix0, 0);
            const float wA0 = (ix0 >= 0) ? (1.f - wx) : wx;  // x0=-1: wx*v[0] via lo half
            const float wB0 = (ix0 >= 0) ? wx : 0.f;
            const u16* pb = planes + ((size_t)(bBatch * 3 + p) << 22);
#pragma unroll
            for (int r = 0; r < 2; ++r) {
                const int iy = iy0 + r;
                const bool vy = (iy >= 0) & (iy < HH);
                const float wrow = (r ? wy : (1.f - wy));
                const float wa = vy ? wrow * wA0 : 0.f;
                const float wb = vy ? wrow * wB0 : 0.f;
                const int iyc = min(max(iy, 0), HH - 1);
                const u16* src = pb + (((size_t)((iyc << 8) | xb)) << 6) + (qd << 4);
                const uint4 d0 = *(const uint4*)src;        // ch qd*8+0..3 (lo/hi = x0/x1)
                const uint4 d1 = *(const uint4*)(src + 8);  // ch qd*8+4..7
#pragma unroll
                for (int j = 0; j < 4; ++j) {
                    const u32 u = (&d0.x)[j];
                    acc[j] = fmaf(wa, bflo(u), fmaf(wb, bfhi(u), acc[j]));
                    const u32 u2 = (&d1.x)[j];
                    acc[4 + j] = fmaf(wa, bflo(u2), fmaf(wb, bfhi(u2), acc[4 + j]));
                }
            }
        }
        u32 w[4];
#pragma unroll
        for (int j = 0; j < 4; ++j)
            w[j] = (u32)f2bf(acc[2 * j]) | ((u32)f2bf(acc[2 * j + 1]) << 16);
        bf16x8 v;
        ((u32*)&v)[0] = w[0]; ((u32*)&v)[1] = w[1];
        ((u32*)&v)[2] = w[2]; ((u32*)&v)[3] = w[3];
        bfr[it] = v;
    }

    // ---- layer 0: K=32, M=64; per-mt interleaved compute+epilogue ----
    {
#pragma unroll
        for (int mt = 0; mt < 4; ++mt) {
            const bf16x8 a0 = *(const bf16x8*)(gW + (mt * 16 + ln) * 32 + qd * 8);
            const float4 bias0 = *(const float4*)(b0 + mt * 16 + qd * 4);
#pragma unroll
            for (int it = 0; it < 2; ++it) {
                floatx4 z = {0.f, 0.f, 0.f, 0.f};
                floatx4 acc = __builtin_amdgcn_mfma_f32_16x16x32_bf16(a0, bfr[it], z, 0, 0, 0);
                const int n = wv * 32 + it * 16 + ln;
                u16 p[4];
#pragma unroll
                for (int r = 0; r < 4; ++r) {
                    float v = acc[r] + (&bias0.x)[r];
                    v = (v >= 0.f) ? v : 0.01f * v;
                    p[r] = f2bf(v);
                }
                uint2 dd = make_uint2((u32)p[0] | ((u32)p[1] << 16), (u32)p[2] | ((u32)p[3] << 16));
                *(uint2*)(sX + n * 72 + mt * 16 + qd * 4) = dd;
            }
        }
    }
    __syncthreads();  // X1 complete

    // ---- layer 1: K=64 (2 chunks), weights streamed, acc packed early ----
    uint2 pk1[2][4];
    {
        const u16* gW1 = gW + 2048;
#pragma unroll
        for (int it = 0; it < 2; ++it) {
            const int n = wv * 32 + it * 16 + ln;
            const bf16x8 f0 = *(const bf16x8*)(sX + n * 72 + qd * 8);
            const bf16x8 f1 = *(const bf16x8*)(sX + n * 72 + 32 + qd * 8);
#pragma unroll
            for (int mt = 0; mt < 4; ++mt) {
                const bf16x8 a10 = *(const bf16x8*)(gW1 + (mt * 16 + ln) * 64 + qd * 8);
                const bf16x8 a11 = *(const bf16x8*)(gW1 + (mt * 16 + ln) * 64 + 32 + qd * 8);
                floatx4 z = {0.f, 0.f, 0.f, 0.f};
                floatx4 t = __builtin_amdgcn_mfma_f32_16x16x32_bf16(a10, f0, z, 0, 0, 0);
                floatx4 acc = __builtin_amdgcn_mfma_f32_16x16x32_bf16(a11, f1, t, 0, 0, 0);
                const float4 bias1 = *(const float4*)(b1 + mt * 16 + qd * 4);
                u16 p[4];
#pragma unroll
                for (int r = 0; r < 4; ++r) {
                    float v = acc[r] + (&bias1.x)[r];
                    v = (v >= 0.f) ? v : 0.01f * v;
                    p[r] = f2bf(v);
                }
                pk1[it][mt] = make_uint2((u32)p[0] | ((u32)p[1] << 16), (u32)p[2] | ((u32)p[3] << 16));
            }
        }
    }
    __syncthreads();  // all waves' X1 reads done; sX may be overwritten

    // write X2 (stride 72)
#pragma unroll
    for (int it = 0; it < 2; ++it) {
        const int n = wv * 32 + it * 16 + ln;
#pragma unroll
        for (int mt = 0; mt < 4; ++mt)
            *(uint2*)(sX + n * 72 + mt * 16 + qd * 4) = pk1[it][mt];
    }
    __syncthreads();  // X2 complete

    // ---- layer 2: K=64, M=48 (3 tiles; m<33 valid), weights streamed ----
    floatx4 acc2[2][3];
    {
        const u16* gW2 = gW + 6144;
#pragma unroll
        for (int it = 0; it < 2; ++it) {
            const int n = wv * 32 + it * 16 + ln;
            const bf16x8 f0 = *(const bf16x8*)(sX + n * 72 + qd * 8);
            const bf16x8 f1 = *(const bf16x8*)(sX + n * 72 + 32 + qd * 8);
#pragma unroll
            for (int mt = 0; mt < 3; ++mt) {
                const bf16x8 a20 = *(const bf16x8*)(gW2 + (mt * 16 + ln) * 64 + qd * 8);
                const bf16x8 a21 = *(const bf16x8*)(gW2 + (mt * 16 + ln) * 64 + 32 + qd * 8);
                floatx4 z = {0.f, 0.f, 0.f, 0.f};
                floatx4 t = __builtin_amdgcn_mfma_f32_16x16x32_bf16(a20, f0, z, 0, 0, 0);
                acc2[it][mt] = __builtin_amdgcn_mfma_f32_16x16x32_bf16(a21, f1, t, 0, 0, 0);
            }
        }
    }
    __syncthreads();  // all waves' X2 reads done; sX may be overwritten

    // epilogue 2 -> sOut fp32 stride 36 (overlays sX); rows wave-private
    float* sOut = (float*)sX;
#pragma unroll
    for (int it = 0; it < 2; ++it) {
        const int n = wv * 32 + it * 16 + ln;
#pragma unroll
        for (int mt = 0; mt < 3; ++mt)
#pragma unroll
            for (int r = 0; r < 4; ++r) {
                const int m = mt * 16 + qd * 4 + r;
                if (m < NOUT) sOut[n * 36 + m] = acc2[it][mt][r] + b2[m];
            }
    }
    __syncthreads();

    // coalesced copy out: MPTS*33 floats
    float* og = out + pbase * NOUT;
    for (int i = tid; i < MPTS * NOUT; i += 256) {
        int n = i / 33, m = i - 33 * n;
        og[i] = sOut[n * 36 + m];
    }
}

// ---------------------------------------------------------------------------
// Fallback: round-1 fused kernel (ws >= dup planes only). 210 us measured.
// ---------------------------------------------------------------------------
__global__ __launch_bounds__(256, 2) void fused_mfma_k(const u16* __restrict__ planes,
                                                       const float* __restrict__ points,
                                                       const float* __restrict__ W0,
                                                       const float* __restrict__ b0,
                                                       const float* __restrict__ W1,
                                                       const float* __restrict__ b1,
                                                       const float* __restrict__ W2,
                                                       const float* __restrict__ b2,
                                                       float* __restrict__ out) {
    __shared__ __align__(16) u16 sW0t[64 * 40];
    __shared__ __align__(16) u16 sW1t[64 * 72];
    __shared__ __align__(16) u16 sW2t[48 * 72];
    __shared__ __align__(16) u16 sR0[MPTS * 72];
    __shared__ __align__(16) u16 sR1[MPTS * 72];
    __shared__ float sB0[64], sB1[64], sB2[33];

    const int tid = threadIdx.x;
    for (int i = tid; i < 32 * 64; i += 256) { int k = i >> 6, m = i & 63; sW0t[m * 40 + k] = f2bf(W0[i]); }
    for (int i = tid; i < 64 * 64; i += 256) { int k = i >> 6, m = i & 63; sW1t[m * 72 + k] = f2bf(W1[i]); }
    for (int i = tid; i < 64 * 33; i += 256) { int k = i / 33, m = i - 33 * k; sW2t[m * 72 + k] = f2bf(W2[i]); }
    if (tid < 64) { sB0[tid] = b0[tid]; sB1[tid] = b1[tid]; }
    if (tid < 33) sB2[tid] = b2[tid];

    const size_t pbase = (size_t)blockIdx.x * MPTS;
    float* sPts = (float*)sR1;  // overlay; dead before epilogue 0
    for (int i = tid; i < MPTS * 3; i += 256) sPts[i] = points[pbase * 3 + i];
    __syncthreads();

    const int bBatch = blockIdx.x >> 12;
#pragma unroll
    for (int t = 0; t < 2; ++t) {
        const int task = t * 256 + tid;
        const int pt = task >> 2, q = task & 3;
        const float px = sPts[pt * 3 + 0];
        const float py = sPts[pt * 3 + 1];
        const float pz = sPts[pt * 3 + 2];
        float acc[8];
#pragma unroll
        for (int j = 0; j < 8; ++j) acc[j] = 0.f;
#pragma unroll
        for (int p = 0; p < PLANES; ++p) {
            const float gx = (p == 2) ? py : px;
            const float gy = (p == 0) ? py : pz;
            const float x = (gx + 1.0f) * 128.0f - 0.5f;
            const float y = (gy + 1.0f) * 128.0f - 0.5f;
            const float xf = floorf(x), yf = floorf(y);
            const float wx = x - xf, wy = y - yf;
            const int ix0 = (int)xf, iy0 = (int)yf;
            const int xb = max(ix0, 0);
            const float ax = (ix0 >= 0) ? (1.f - wx) : wx;
            const float bx = (ix0 >= 0) ? wx : 0.f;
            const u16* pb = planes + ((size_t)(bBatch * 3 + p) << 22);
#pragma unroll
            for (int r = 0; r < 2; ++r) {
                const int iy = iy0 + r;
                const bool vy = (iy >= 0) & (iy < HH);
                const float wrow = (r ? wy : (1.f - wy));
                const float wa = vy ? wrow * ax : 0.f;
                const float wb = vy ? wrow * bx : 0.f;
                const int iyc = min(max(iy, 0), HH - 1);
                const u16* src = pb + (((size_t)((iyc << 8) | xb)) << 6) + (q << 4);
                const uint4 d0 = *(const uint4*)src;
                const uint4 d1 = *(const uint4*)(src + 8);
#pragma unroll
                for (int j = 0; j < 4; ++j) {
                    const u32 u = (&d0.x)[j];
                    acc[j] = fmaf(wa, bflo(u), fmaf(wb, bfhi(u), acc[j]));
                    const u32 u2 = (&d1.x)[j];
                    acc[4 + j] = fmaf(wa, bflo(u2), fmaf(wb, bfhi(u2), acc[4 + j]));
                }
            }
        }
        uint4 o;
        o.x = (u32)f2bf(acc[0]) | ((u32)f2bf(acc[1]) << 16);
        o.y = (u32)f2bf(acc[2]) | ((u32)f2bf(acc[3]) << 16);
        o.z = (u32)f2bf(acc[4]) | ((u32)f2bf(acc[5]) << 16);
        o.w = (u32)f2bf(acc[6]) | ((u32)f2bf(acc[7]) << 16);
        *(uint4*)(sR0 + pt * 40 + q * 8) = o;
    }
    __syncthreads();

    const int lane = tid & 63, wv = tid >> 6;
    const int ln = lane & 15, qd = lane >> 4;

    bf16x8 a0[4];
#pragma unroll
    for (int mt = 0; mt < 4; ++mt)
        a0[mt] = *(const bf16x8*)(sW0t + (mt * 16 + ln) * 40 + qd * 8);
    bf16x8 bx0[2];
#pragma unroll
    for (int nt = 0; nt < 2; ++nt)
        bx0[nt] = *(const bf16x8*)(sR0 + (wv * 32 + nt * 16 + ln) * 40 + qd * 8);
    floatx4 acc0[2][4];
#pragma unroll
    for (int nt = 0; nt < 2; ++nt)
#pragma unroll
        for (int mt = 0; mt < 4; ++mt) {
            floatx4 z = {0.f, 0.f, 0.f, 0.f};
            acc0[nt][mt] = __builtin_amdgcn_mfma_f32_16x16x32_bf16(a0[mt], bx0[nt], z, 0, 0, 0);
        }
#pragma unroll
    for (int nt = 0; nt < 2; ++nt) {
        const int n = wv * 32 + nt * 16 + ln;
#pragma unroll
        for (int mt = 0; mt < 4; ++mt) {
            u16 p[4];
#pragma unroll
            for (int r = 0; r < 4; ++r) {
                const int m = mt * 16 + qd * 4 + r;
                float v = acc0[nt][mt][r] + sB0[m];
                v = (v >= 0.f) ? v : 0.01f * v;
                p[r] = f2bf(v);
            }
            uint2 dd = make_uint2((u32)p[0] | ((u32)p[1] << 16), (u32)p[2] | ((u32)p[3] << 16));
            *(uint2*)(sR1 + n * 72 + mt * 16 + qd * 4) = dd;
        }
    }

    bf16x8 a1[4][2];
#pragma unroll
    for (int mt = 0; mt < 4; ++mt)
#pragma unroll
        for (int c = 0; c < 2; ++c)
            a1[mt][c] = *(const bf16x8*)(sW1t + (mt * 16 + ln) * 72 + c * 32 + qd * 8);
    floatx4 acc1[2][4];
#pragma unroll
    for (int nt = 0; nt < 2; ++nt) {
        const int n = wv * 32 + nt * 16 + ln;
        bf16x8 bf0 = *(const bf16x8*)(sR1 + n * 72 + qd * 8);
        bf16x8 bf1 = *(const bf16x8*)(sR1 + n * 72 + 32 + qd * 8);
#pragma unroll
        for (int mt = 0; mt < 4; ++mt) {
            floatx4 z = {0.f, 0.f, 0.f, 0.f};
            floatx4 t = __builtin_amdgcn_mfma_f32_16x16x32_bf16(a1[mt][0], bf0, z, 0, 0, 0);
            acc1[nt][mt] = __builtin_amdgcn_mfma_f32_16x16x32_bf16(a1[mt][1], bf1, t, 0, 0, 0);
        }
    }
    __syncthreads();

#pragma unroll
    for (int nt = 0; nt < 2; ++nt) {
        const int n = wv * 32 + nt * 16 + ln;
#pragma unroll
        for (int mt = 0; mt < 4; ++mt) {
            u16 p[4];
#pragma unroll
            for (int r = 0; r < 4; ++r) {
                const int m = mt * 16 + qd * 4 + r;
                float v = acc1[nt][mt][r] + sB1[m];
                v = (v >= 0.f) ? v : 0.01f * v;
                p[r] = f2bf(v);
            }
            uint2 dd = make_uint2((u32)p[0] | ((u32)p[1] << 16), (u32)p[2] | ((u32)p[3] << 16));
            *(uint2*)(sR0 + n * 72 + mt * 16 + qd * 4) = dd;
        }
    }

    bf16x8 a2[3][2];
#pragma unroll
    for (int mt = 0; mt < 3; ++mt)
#pragma unroll
        for (int c = 0; c < 2; ++c)
            a2[mt][c] = *(const bf16x8*)(sW2t + (mt * 16 + ln) * 72 + c * 32 + qd * 8);
    floatx4 acc2[2][3];
#pragma unroll
    for (int nt = 0; nt < 2; ++nt) {
        const int n = wv * 32 + nt * 16 + ln;
        bf16x8 bf0 = *(const bf16x8*)(sR0 + n * 72 + qd * 8);
        bf16x8 bf1 = *(const bf16x8*)(sR0 + n * 72 + 32 + qd * 8);
#pragma unroll
        for (int mt = 0; mt < 3; ++mt) {
            floatx4 z = {0.f, 0.f, 0.f, 0.f};
            floatx4 t = __builtin_amdgcn_mfma_f32_16x16x32_bf16(a2[mt][0], bf0, z, 0, 0, 0);
            acc2[nt][mt] = __builtin_amdgcn_mfma_f32_16x16x32_bf16(a2[mt][1], bf1, t, 0, 0, 0);
        }
    }
    __syncthreads();

    float* sOut = (float*)sR1;
#pragma unroll
    for (int nt = 0; nt < 2; ++nt) {
        const int n = wv * 32 + nt * 16 + ln;
#pragma unroll
        for (int mt = 0; mt < 3; ++mt)
#pragma unroll
            for (int r = 0; r < 4; ++r) {
                const int m = mt * 16 + qd * 4 + r;
                if (m < NOUT) sOut[n * 36 + m] = acc2[nt][mt][r] + sB2[m];
            }
    }
    __syncthreads();

    float* og = out + pbase * NOUT;
    for (int i = tid; i < MPTS * NOUT; i += 256) {
        int n = i / 33, m = i - 33 * n;
        og[i] = sOut[n * 36 + m];
    }
}

// ---------------------------------------------------------------------------
// Fallback: fully scalar, no workspace.
// ---------------------------------------------------------------------------
__global__ __launch_bounds__(256) void fused_fallback_k(const float* __restrict__ planes,
                                                        const float* __restrict__ points,
                                                        const float* __restrict__ W0,
                                                        const float* __restrict__ b0,
                                                        const float* __restrict__ W1,
                                                        const float* __restrict__ b1,
                                                        const float* __restrict__ W2,
                                                        const float* __restrict__ b2,
                                                        float* __restrict__ out) {
    const int tid = threadIdx.x;
    const int pgl = blockIdx.x * 256 + tid;
    const int b = pgl >> 19;
    const float px = points[(size_t)pgl * 3 + 0];
    const float py = points[(size_t)pgl * 3 + 1];
    const float pz = points[(size_t)pgl * 3 + 2];
    float feat[CP];
#pragma unroll
    for (int c = 0; c < CP; ++c) feat[c] = 0.f;
#pragma unroll
    for (int p = 0; p < PLANES; ++p) {
        const float gx = (p == 2) ? py : px;
        const float gy = (p == 0) ? py : pz;
        const float x = (gx + 1.0f) * 128.0f - 0.5f;
        const float y = (gy + 1.0f) * 128.0f - 0.5f;
        const float xf = floorf(x), yf = floorf(y);
        const float wx = x - xf, wy = y - yf;
        const int ix0 = (int)xf, iy0 = (int)yf;
        const float* pb = planes + (((size_t)(b * 96 + p * 32)) << 16);
        auto corner = [&](int ix, int iy, float w) {
            const bool v = (ix >= 0) & (ix < WW) & (iy >= 0) & (iy < HH);
            w = v ? w : 0.f;
            const int ixc = min(max(ix, 0), WW - 1);
            const int iyc = min(max(iy, 0), HH - 1);
            const int yx = (iyc << 8) | ixc;
            const float* src = pb + yx;
#pragma unroll
            for (int c = 0; c < CP; ++c) feat[c] = fmaf(w, src[(size_t)c << 16], feat[c]);
        };
        corner(ix0,     iy0,     (1.f - wx) * (1.f - wy));
        corner(ix0 + 1, iy0,     wx * (1.f - wy));
        corner(ix0,     iy0 + 1, (1.f - wx) * wy);
        corner(ix0 + 1, iy0 + 1, wx * wy);
    }
    float h0[HID];
#pragma unroll
    for (int j = 0; j < HID; ++j) h0[j] = b0[j];
    for (int k = 0; k < CP; ++k) {
        const float f = feat[k];
#pragma unroll
        for (int j = 0; j < HID; ++j) h0[j] = fmaf(f, W0[k * HID + j], h0[j]);
    }
#pragma unroll
    for (int j = 0; j < HID; ++j) h0[j] = (h0[j] >= 0.f) ? h0[j] : 0.01f * h0[j];
    float h1[HID];
#pragma unroll
    for (int j = 0; j < HID; ++j) h1[j] = b1[j];
    for (int k = 0; k < HID; ++k) {
        const float f = h0[k];
#pragma unroll
        for (int j = 0; j < HID; ++j) h1[j] = fmaf(f, W1[k * HID + j], h1[j]);
    }
#pragma unroll
    for (int j = 0; j < HID; ++j) h1[j] = (h1[j] >= 0.f) ? h1[j] : 0.01f * h1[j];
    float o[NOUT];
#pragma unroll
    for (int j = 0; j < NOUT; ++j) o[j] = b2[j];
    for (int k = 0; k < HID; ++k) {
        const float f = h1[k];
#pragma unroll
        for (int j = 0; j < NOUT; ++j) o[j] = fmaf(f, W2[k * NOUT + j], o[j]);
    }
    float* op = out + (size_t)pgl * NOUT;
#pragma unroll
    for (int j = 0; j < NOUT; ++j) op[j] = o[j];
}

// ---------------------------------------------------------------------------
extern "C" void kernel_launch(void* const* d_in, const int* in_sizes, int n_in,
                              void* d_out, int out_size, void* d_ws, size_t ws_size,
                              hipStream_t stream) {
    const float* triplane = (const float*)d_in[0];
    const float* points   = (const float*)d_in[1];
    const float* W0 = (const float*)d_in[2];
    const float* b0 = (const float*)d_in[3];
    const float* W1 = (const float*)d_in[4];
    const float* b1 = (const float*)d_in[5];
    const float* W2 = (const float*)d_in[6];
    const float* b2 = (const float*)d_in[7];
    float* out = (float*)d_out;

    const size_t dupElems = (size_t)BATCH * PLANES * PLANE_ELEMS_DUP;
    const size_t needDup  = dupElems * sizeof(u16);                    // 50.3 MB
    const size_t needAll  = needDup + GW_ELEMS * sizeof(u16);          // + 18.4 KB

    if (d_ws != nullptr && ws_size >= needAll) {
        u16* planesW = (u16*)d_ws;
        u16* gW      = planesW + dupElems;
        transpose_dup_k<<<(BATCH * PLANES * HWSZ) / 256, 256, 0, stream>>>(triplane, planesW);
        prep_w_k<<<GW_ELEMS / 256, 256, 0, stream>>>(W0, W1, W2, gW);
        fused5_k<<<NPTS_TOTAL / MPTS, 256, 0, stream>>>(planesW, gW, points, b0, b1, b2, out);
    } else if (d_ws != nullptr && ws_size >= needDup) {
        u16* planesW = (u16*)d_ws;
        transpose_dup_k<<<(BATCH * PLANES * HWSZ) / 256, 256, 0, stream>>>(triplane, planesW);
        fused_mfma_k<<<NPTS_TOTAL / MPTS, 256, 0, stream>>>(planesW, points, W0, b0, W1, b1, W2, b2, out);
    } else {
        fused_fallback_k<<<NPTS_TOTAL / 256, 256, 0, stream>>>(
            triplane, points, W0, b0, W1, b1, W2, b2, out);
    }
}

// Round 6
// 365.892 us; speedup vs baseline: 1.0598x; 1.0231x over previous
//
#include <hip/hip_runtime.h>

// Problem constants
#define BATCH 2
#define PLANES 3
#define CP 32
#define HH 256
#define WW 256
#define HWSZ 65536
#define HID 64
#define NOUT 33
#define NPTS_TOTAL 1048576
#define PLANE_ELEMS 2097152      // HWSZ*CP (u16 elems per plane, non-dup layout)
#define PLANE_ELEMS_DUP 4194304  // HWSZ*CP*2 (u16 elems per plane, dup-pair layout)
#define MPTS 128                 // points per fused block
#define GW_ELEMS 9216            // 2048 (W0t) + 4096 (W1t) + 3072 (W2t) bf16

typedef unsigned int u32;
typedef unsigned short u16;
typedef float floatx4 __attribute__((ext_vector_type(4)));
typedef short bf16x8 __attribute__((ext_vector_type(8)));

static __device__ __forceinline__ u16 f2bf(float f) {
    u32 u = __float_as_uint(f);
    return (u16)((u + 0x7fffu + ((u >> 16) & 1u)) >> 16);  // RNE
}
static __device__ __forceinline__ float bflo(u32 u) { return __uint_as_float(u << 16); }
static __device__ __forceinline__ float bfhi(u32 u) { return __uint_as_float(u & 0xffff0000u); }

// ---------------------------------------------------------------------------
// Kernel 1: transpose triplane (B,96,H,W) fp32 -> dup-pair layout
// (B*3, H, W, 32ch, 2) bf16: each 128-B pixel-block holds (v[x], v[x+1]) per
// channel -> any bilinear x-pair is ONE fully-utilized cache line.
// Block x=255 bakes in v1=0 (x+1 OOB).
// ---------------------------------------------------------------------------
__global__ __launch_bounds__(256) void transpose_dup_k(const float* __restrict__ tp,
                                                       u16* __restrict__ out) {
    int idx = blockIdx.x * 256 + threadIdx.x;  // < 6*65536
    int bp = idx >> 16;
    int yx = idx & 65535;
    int x = yx & 255;
    int b = bp / 3, p = bp - 3 * b;
    const float* src = tp + (((size_t)(b * 96 + p * 32)) << 16) + yx;
    const bool hasx1 = (x < 255);
    u16 v0[32], v1[32];
#pragma unroll
    for (int c = 0; c < 32; ++c) {
        v0[c] = f2bf(src[(size_t)c << 16]);
        v1[c] = hasx1 ? f2bf(src[((size_t)c << 16) + 1]) : (u16)0;
    }
    uint4* dst = (uint4*)(out + ((size_t)idx << 6));  // 64 u16 = 128 B per block
#pragma unroll
    for (int i = 0; i < 8; ++i) {
        uint4 w;
        w.x = (u32)v0[4 * i + 0] | ((u32)v1[4 * i + 0] << 16);
        w.y = (u32)v0[4 * i + 1] | ((u32)v1[4 * i + 1] << 16);
        w.z = (u32)v0[4 * i + 2] | ((u32)v1[4 * i + 2] << 16);
        w.w = (u32)v0[4 * i + 3] | ((u32)v1[4 * i + 3] << 16);
        dst[i] = w;
    }
}

// ---------------------------------------------------------------------------
// Kernel 1b: pre-tile MLP weights into fragment-major bf16 blob (once).
// gW[0..2048)      = W0t[m][k] (m<64,k<32):  gW[m*32+k]        = W0[k*64+m]
// gW[2048..6144)   = W1t[m][k] (64x64):      gW[2048+m*64+k]   = W1[k*64+m]
// gW[6144..9216)   = W2t[m][k] (m<48,k<64):  gW[6144+m*64+k]   = W2[k*33+m] (m<33) else 0
// ---------------------------------------------------------------------------
__global__ __launch_bounds__(256) void prep_w_k(const float* __restrict__ W0,
                                                const float* __restrict__ W1,
                                                const float* __restrict__ W2,
                                                u16* __restrict__ gW) {
    int i = blockIdx.x * 256 + threadIdx.x;  // < GW_ELEMS
    if (i < 2048) {
        int m = i >> 5, k = i & 31;
        gW[i] = f2bf(W0[k * 64 + m]);
    } else if (i < 6144) {
        int j = i - 2048;
        int m = j >> 6, k = j & 63;
        gW[i] = f2bf(W1[k * 64 + m]);
    } else {
        int j = i - 6144;
        int m = j >> 6, k = j & 63;
        gW[i] = (m < NOUT) ? f2bf(W2[k * NOUT + m]) : (u16)0;
    }
}

// ---------------------------------------------------------------------------
// Kernel 2: fused gather + MFMA MLP, v5.
//  - MLP code in the register-frugal fused3 style (upfront weight-frag
//    arrays; measured 56 natural VGPR at cap 128) -> NO launch_bounds cap
//    below natural demand (the (256,4) bound = 128 regs).  At <=64 VGPR the
//    HW runs 8 waves/SIMD on its own (occupancy steps at 64/128/256).
//  - Single LDS buffer sX (128*72 u16 = 18.4 KB) time-shared X1 -> X2 ->
//    sOut with barriers -> 8 blocks/CU (147 KB).
//  - Cross-barrier state minimized: layer-1 output packed to bf16 pk1[2][4]
//    (16 regs) BEFORE the X1-read/X2-write barrier.
// MFMA semantics (verified): D[m][n] = sum_k Wt[m][k]*X[n][k],
// A[m=lane&15][k=qd*8+j], B[k=qd*8+j][n=lane&15], D: col=lane&15(n),
// row=qd*4+r(m). Padded LDS stride 72 keeps b128 reads conflict-free.
// ---------------------------------------------------------------------------
__global__ __launch_bounds__(256, 4) void fused6_k(const u16* __restrict__ planes,
                                                   const u16* __restrict__ gW,
                                                   const float* __restrict__ points,
                                                   const float* __restrict__ b0,
                                                   const float* __restrict__ b1,
                                                   const float* __restrict__ b2,
                                                   float* __restrict__ out) {
    __shared__ __align__(16) u16 sX[MPTS * 72];   // X1, then X2, then sOut (f32 stride 36)

    const int tid = threadIdx.x;
    const int lane = tid & 63, wv = tid >> 6;
    const int ln = lane & 15, qd = lane >> 4;
    const size_t pbase = (size_t)blockIdx.x * MPTS;
    const int bBatch = blockIdx.x >> 12;  // 4096 blocks per batch

    // ---- gather phase: produce layer-0 B-fragments directly in registers ----
    bf16x8 bfr[2];
#pragma unroll
    for (int it = 0; it < 2; ++it) {
        const int pt = wv * 32 + it * 16 + ln;
        const size_t gpt = pbase + pt;
        const float px = points[gpt * 3 + 0];
        const float py = points[gpt * 3 + 1];
        const float pz = points[gpt * 3 + 2];
        float acc[8];
#pragma unroll
        for (int j = 0; j < 8; ++j) acc[j] = 0.f;
#pragma unroll
        for (int p = 0; p < PLANES; ++p) {
            const float gx = (p == 2) ? py : px;
            const float gy = (p == 0) ? py : pz;
            const float x = (gx + 1.0f) * 128.0f - 0.5f;
            const float y = (gy + 1.0f) * 128.0f - 0.5f;
            const float xf = floorf(x), yf = floorf(y);
            const float wx = x - xf, wy = y - yf;
            const int ix0 = (int)xf, iy0 = (int)yf;          // in [-1,255]
            const int xb = max(ix0, 0);
            const float wA0 = (ix0 >= 0) ? (1.f - wx) : wx;  // x0=-1: wx*v[0] via lo half
            const float wB0 = (ix0 >= 0) ? wx : 0.f;
            const u16* pb = planes + ((size_t)(bBatch * 3 + p) << 22);
#pragma unroll
            for (int r = 0; r < 2; ++r) {
                const int iy = iy0 + r;
                const bool vy = (iy >= 0) & (iy < HH);
                const float wrow = (r ? wy : (1.f - wy));
                const float wa = vy ? wrow * wA0 : 0.f;
                const float wb = vy ? wrow * wB0 : 0.f;
                const int iyc = min(max(iy, 0), HH - 1);
                const u16* src = pb + (((size_t)((iyc << 8) | xb)) << 6) + (qd << 4);
                const uint4 d0 = *(const uint4*)src;        // ch qd*8+0..3 (lo/hi = x0/x1)
                const uint4 d1 = *(const uint4*)(src + 8);  // ch qd*8+4..7
#pragma unroll
                for (int j = 0; j < 4; ++j) {
                    const u32 u = (&d0.x)[j];
                    acc[j] = fmaf(wa, bflo(u), fmaf(wb, bfhi(u), acc[j]));
                    const u32 u2 = (&d1.x)[j];
                    acc[4 + j] = fmaf(wa, bflo(u2), fmaf(wb, bfhi(u2), acc[4 + j]));
                }
            }
        }
        u32 w[4];
#pragma unroll
        for (int j = 0; j < 4; ++j)
            w[j] = (u32)f2bf(acc[2 * j]) | ((u32)f2bf(acc[2 * j + 1]) << 16);
        bf16x8 v;
        ((u32*)&v)[0] = w[0]; ((u32*)&v)[1] = w[1];
        ((u32*)&v)[2] = w[2]; ((u32*)&v)[3] = w[3];
        bfr[it] = v;
    }

    // ---- layer 0: K=32, M=64 (4 tiles); per-mt interleaved epilogue ----
    {
#pragma unroll
        for (int mt = 0; mt < 4; ++mt) {
            const bf16x8 a0 = *(const bf16x8*)(gW + (mt * 16 + ln) * 32 + qd * 8);
            const float4 bias0 = *(const float4*)(b0 + mt * 16 + qd * 4);
#pragma unroll
            for (int it = 0; it < 2; ++it) {
                floatx4 z = {0.f, 0.f, 0.f, 0.f};
                floatx4 acc = __builtin_amdgcn_mfma_f32_16x16x32_bf16(a0, bfr[it], z, 0, 0, 0);
                const int n = wv * 32 + it * 16 + ln;
                u16 p[4];
#pragma unroll
                for (int r = 0; r < 4; ++r) {
                    float v = acc[r] + (&bias0.x)[r];
                    v = (v >= 0.f) ? v : 0.01f * v;
                    p[r] = f2bf(v);
                }
                uint2 dd = make_uint2((u32)p[0] | ((u32)p[1] << 16), (u32)p[2] | ((u32)p[3] << 16));
                *(uint2*)(sX + n * 72 + mt * 16 + qd * 4) = dd;
            }
        }
    }
    __syncthreads();  // X1 complete

    // ---- layer 1: K=64 (2 chunks); upfront weight frags (fused3 style);
    //      output packed to bf16 BEFORE the overwrite barrier ----
    uint2 pk1[2][4];
    {
        const u16* gW1 = gW + 2048;
        bf16x8 a1[4][2];
#pragma unroll
        for (int mt = 0; mt < 4; ++mt)
#pragma unroll
            for (int c = 0; c < 2; ++c)
                a1[mt][c] = *(const bf16x8*)(gW1 + (mt * 16 + ln) * 64 + c * 32 + qd * 8);
#pragma unroll
        for (int it = 0; it < 2; ++it) {
            const int n = wv * 32 + it * 16 + ln;
            const bf16x8 f0 = *(const bf16x8*)(sX + n * 72 + qd * 8);
            const bf16x8 f1 = *(const bf16x8*)(sX + n * 72 + 32 + qd * 8);
#pragma unroll
            for (int mt = 0; mt < 4; ++mt) {
                floatx4 z = {0.f, 0.f, 0.f, 0.f};
                floatx4 t = __builtin_amdgcn_mfma_f32_16x16x32_bf16(a1[mt][0], f0, z, 0, 0, 0);
                floatx4 acc = __builtin_amdgcn_mfma_f32_16x16x32_bf16(a1[mt][1], f1, t, 0, 0, 0);
                const float4 bias1 = *(const float4*)(b1 + mt * 16 + qd * 4);
                u16 p[4];
#pragma unroll
                for (int r = 0; r < 4; ++r) {
                    float v = acc[r] + (&bias1.x)[r];
                    v = (v >= 0.f) ? v : 0.01f * v;
                    p[r] = f2bf(v);
                }
                pk1[it][mt] = make_uint2((u32)p[0] | ((u32)p[1] << 16), (u32)p[2] | ((u32)p[3] << 16));
            }
        }
    }
    __syncthreads();  // all waves' X1 reads done; sX may be overwritten

    // write X2 (stride 72)
#pragma unroll
    for (int it = 0; it < 2; ++it) {
        const int n = wv * 32 + it * 16 + ln;
#pragma unroll
        for (int mt = 0; mt < 4; ++mt)
            *(uint2*)(sX + n * 72 + mt * 16 + qd * 4) = pk1[it][mt];
    }
    __syncthreads();  // X2 complete

    // ---- layer 2: K=64, M=48 (3 tiles; m<33 valid); upfront weight frags ----
    floatx4 acc2[2][3];
    {
        const u16* gW2 = gW + 6144;
        bf16x8 a2[3][2];
#pragma unroll
        for (int mt = 0; mt < 3; ++mt)
#pragma unroll
            for (int c = 0; c < 2; ++c)
                a2[mt][c] = *(const bf16x8*)(gW2 + (mt * 16 + ln) * 64 + c * 32 + qd * 8);
#pragma unroll
        for (int it = 0; it < 2; ++it) {
            const int n = wv * 32 + it * 16 + ln;
            const bf16x8 f0 = *(const bf16x8*)(sX + n * 72 + qd * 8);
            const bf16x8 f1 = *(const bf16x8*)(sX + n * 72 + 32 + qd * 8);
#pragma unroll
            for (int mt = 0; mt < 3; ++mt) {
                floatx4 z = {0.f, 0.f, 0.f, 0.f};
                floatx4 t = __builtin_amdgcn_mfma_f32_16x16x32_bf16(a2[mt][0], f0, z, 0, 0, 0);
                acc2[it][mt] = __builtin_amdgcn_mfma_f32_16x16x32_bf16(a2[mt][1], f1, t, 0, 0, 0);
            }
        }
    }
    __syncthreads();  // all waves' X2 reads done; sX may be overwritten

    // epilogue 2 -> sOut fp32 stride 36 (overlays sX); rows wave-private
    float* sOut = (float*)sX;
#pragma unroll
    for (int it = 0; it < 2; ++it) {
        const int n = wv * 32 + it * 16 + ln;
#pragma unroll
        for (int mt = 0; mt < 3; ++mt)
#pragma unroll
            for (int r = 0; r < 4; ++r) {
                const int m = mt * 16 + qd * 4 + r;
                if (m < NOUT) sOut[n * 36 + m] = acc2[it][mt][r] + b2[m];
            }
    }
    __syncthreads();

    // coalesced copy out: MPTS*33 floats
    float* og = out + pbase * NOUT;
    for (int i = tid; i < MPTS * NOUT; i += 256) {
        int n = i / 33, m = i - 33 * n;
        og[i] = sOut[n * 36 + m];
    }
}

// ---------------------------------------------------------------------------
// Fallback: round-1 fused kernel (ws >= dup planes only). 210 us measured.
// ---------------------------------------------------------------------------
__global__ __launch_bounds__(256, 2) void fused_mfma_k(const u16* __restrict__ planes,
                                                       const float* __restrict__ points,
                                                       const float* __restrict__ W0,
                                                       const float* __restrict__ b0,
                                                       const float* __restrict__ W1,
                                                       const float* __restrict__ b1,
                                                       const float* __restrict__ W2,
                                                       const float* __restrict__ b2,
                                                       float* __restrict__ out) {
    __shared__ __align__(16) u16 sW0t[64 * 40];
    __shared__ __align__(16) u16 sW1t[64 * 72];
    __shared__ __align__(16) u16 sW2t[48 * 72];
    __shared__ __align__(16) u16 sR0[MPTS * 72];
    __shared__ __align__(16) u16 sR1[MPTS * 72];
    __shared__ float sB0[64], sB1[64], sB2[33];

    const int tid = threadIdx.x;
    for (int i = tid; i < 32 * 64; i += 256) { int k = i >> 6, m = i & 63; sW0t[m * 40 + k] = f2bf(W0[i]); }
    for (int i = tid; i < 64 * 64; i += 256) { int k = i >> 6, m = i & 63; sW1t[m * 72 + k] = f2bf(W1[i]); }
    for (int i = tid; i < 64 * 33; i += 256) { int k = i / 33, m = i - 33 * k; sW2t[m * 72 + k] = f2bf(W2[i]); }
    if (tid < 64) { sB0[tid] = b0[tid]; sB1[tid] = b1[tid]; }
    if (tid < 33) sB2[tid] = b2[tid];

    const size_t pbase = (size_t)blockIdx.x * MPTS;
    float* sPts = (float*)sR1;  // overlay; dead before epilogue 0
    for (int i = tid; i < MPTS * 3; i += 256) sPts[i] = points[pbase * 3 + i];
    __syncthreads();

    const int bBatch = blockIdx.x >> 12;
#pragma unroll
    for (int t = 0; t < 2; ++t) {
        const int task = t * 256 + tid;
        const int pt = task >> 2, q = task & 3;
        const float px = sPts[pt * 3 + 0];
        const float py = sPts[pt * 3 + 1];
        const float pz = sPts[pt * 3 + 2];
        float acc[8];
#pragma unroll
        for (int j = 0; j < 8; ++j) acc[j] = 0.f;
#pragma unroll
        for (int p = 0; p < PLANES; ++p) {
            const float gx = (p == 2) ? py : px;
            const float gy = (p == 0) ? py : pz;
            const float x = (gx + 1.0f) * 128.0f - 0.5f;
            const float y = (gy + 1.0f) * 128.0f - 0.5f;
            const float xf = floorf(x), yf = floorf(y);
            const float wx = x - xf, wy = y - yf;
            const int ix0 = (int)xf, iy0 = (int)yf;
            const int xb = max(ix0, 0);
            const float ax = (ix0 >= 0) ? (1.f - wx) : wx;
            const float bx = (ix0 >= 0) ? wx : 0.f;
            const u16* pb = planes + ((size_t)(bBatch * 3 + p) << 22);
#pragma unroll
            for (int r = 0; r < 2; ++r) {
                const int iy = iy0 + r;
                const bool vy = (iy >= 0) & (iy < HH);
                const float wrow = (r ? wy : (1.f - wy));
                const float wa = vy ? wrow * ax : 0.f;
                const float wb = vy ? wrow * bx : 0.f;
                const int iyc = min(max(iy, 0), HH - 1);
                const u16* src = pb + (((size_t)((iyc << 8) | xb)) << 6) + (q << 4);
                const uint4 d0 = *(const uint4*)src;
                const uint4 d1 = *(const uint4*)(src + 8);
#pragma unroll
                for (int j = 0; j < 4; ++j) {
                    const u32 u = (&d0.x)[j];
                    acc[j] = fmaf(wa, bflo(u), fmaf(wb, bfhi(u), acc[j]));
                    const u32 u2 = (&d1.x)[j];
                    acc[4 + j] = fmaf(wa, bflo(u2), fmaf(wb, bfhi(u2), acc[4 + j]));
                }
            }
        }
        uint4 o;
        o.x = (u32)f2bf(acc[0]) | ((u32)f2bf(acc[1]) << 16);
        o.y = (u32)f2bf(acc[2]) | ((u32)f2bf(acc[3]) << 16);
        o.z = (u32)f2bf(acc[4]) | ((u32)f2bf(acc[5]) << 16);
        o.w = (u32)f2bf(acc[6]) | ((u32)f2bf(acc[7]) << 16);
        *(uint4*)(sR0 + pt * 40 + q * 8) = o;
    }
    __syncthreads();

    const int lane = tid & 63, wv = tid >> 6;
    const int ln = lane & 15, qd = lane >> 4;

    bf16x8 a0[4];
#pragma unroll
    for (int mt = 0; mt < 4; ++mt)
        a0[mt] = *(const bf16x8*)(sW0t + (mt * 16 + ln) * 40 + qd * 8);
    bf16x8 bx0[2];
#pragma unroll
    for (int nt = 0; nt < 2; ++nt)
        bx0[nt] = *(const bf16x8*)(sR0 + (wv * 32 + nt * 16 + ln) * 40 + qd * 8);
    floatx4 acc0[2][4];
#pragma unroll
    for (int nt = 0; nt < 2; ++nt)
#pragma unroll
        for (int mt = 0; mt < 4; ++mt) {
            floatx4 z = {0.f, 0.f, 0.f, 0.f};
            acc0[nt][mt] = __builtin_amdgcn_mfma_f32_16x16x32_bf16(a0[mt], bx0[nt], z, 0, 0, 0);
        }
#pragma unroll
    for (int nt = 0; nt < 2; ++nt) {
        const int n = wv * 32 + nt * 16 + ln;
#pragma unroll
        for (int mt = 0; mt < 4; ++mt) {
            u16 p[4];
#pragma unroll
            for (int r = 0; r < 4; ++r) {
                const int m = mt * 16 + qd * 4 + r;
                float v = acc0[nt][mt][r] + sB0[m];
                v = (v >= 0.f) ? v : 0.01f * v;
                p[r] = f2bf(v);
            }
            uint2 dd = make_uint2((u32)p[0] | ((u32)p[1] << 16), (u32)p[2] | ((u32)p[3] << 16));
            *(uint2*)(sR1 + n * 72 + mt * 16 + qd * 4) = dd;
        }
    }

    bf16x8 a1[4][2];
#pragma unroll
    for (int mt = 0; mt < 4; ++mt)
#pragma unroll
        for (int c = 0; c < 2; ++c)
            a1[mt][c] = *(const bf16x8*)(sW1t + (mt * 16 + ln) * 72 + c * 32 + qd * 8);
    floatx4 acc1[2][4];
#pragma unroll
    for (int nt = 0; nt < 2; ++nt) {
        const int n = wv * 32 + nt * 16 + ln;
        bf16x8 bf0 = *(const bf16x8*)(sR1 + n * 72 + qd * 8);
        bf16x8 bf1 = *(const bf16x8*)(sR1 + n * 72 + 32 + qd * 8);
#pragma unroll
        for (int mt = 0; mt < 4; ++mt) {
            floatx4 z = {0.f, 0.f, 0.f, 0.f};
            floatx4 t = __builtin_amdgcn_mfma_f32_16x16x32_bf16(a1[mt][0], bf0, z, 0, 0, 0);
            acc1[nt][mt] = __builtin_amdgcn_mfma_f32_16x16x32_bf16(a1[mt][1], bf1, t, 0, 0, 0);
        }
    }
    __syncthreads();

#pragma unroll
    for (int nt = 0; nt < 2; ++nt) {
        const int n = wv * 32 + nt * 16 + ln;
#pragma unroll
        for (int mt = 0; mt < 4; ++mt) {
            u16 p[4];
#pragma unroll
            for (int r = 0; r < 4; ++r) {
                const int m = mt * 16 + qd * 4 + r;
                float v = acc1[nt][mt][r] + sB1[m];
                v = (v >= 0.f) ? v : 0.01f * v;
                p[r] = f2bf(v);
            }
            uint2 dd = make_uint2((u32)p[0] | ((u32)p[1] << 16), (u32)p[2] | ((u32)p[3] << 16));
            *(uint2*)(sR0 + n * 72 + mt * 16 + qd * 4) = dd;
        }
    }

    bf16x8 a2[3][2];
#pragma unroll
    for (int mt = 0; mt < 3; ++mt)
#pragma unroll
        for (int c = 0; c < 2; ++c)
            a2[mt][c] = *(const bf16x8*)(sW2t + (mt * 16 + ln) * 72 + c * 32 + qd * 8);
    floatx4 acc2[2][3];
#pragma unroll
    for (int nt = 0; nt < 2; ++nt) {
        const int n = wv * 32 + nt * 16 + ln;
        bf16x8 bf0 = *(const bf16x8*)(sR0 + n * 72 + qd * 8);
        bf16x8 bf1 = *(const bf16x8*)(sR0 + n * 72 + 32 + qd * 8);
#pragma unroll
        for (int mt = 0; mt < 3; ++mt) {
            floatx4 z = {0.f, 0.f, 0.f, 0.f};
            floatx4 t = __builtin_amdgcn_mfma_f32_16x16x32_bf16(a2[mt][0], bf0, z, 0, 0, 0);
            acc2[nt][mt] = __builtin_amdgcn_mfma_f32_16x16x32_bf16(a2[mt][1], bf1, t, 0, 0, 0);
        }
    }
    __syncthreads();

    float* sOut = (float*)sR1;
#pragma unroll
    for (int nt = 0; nt < 2; ++nt) {
        const int n = wv * 32 + nt * 16 + ln;
#pragma unroll
        for (int mt = 0; mt < 3; ++mt)
#pragma unroll
            for (int r = 0; r < 4; ++r) {
                const int m = mt * 16 + qd * 4 + r;
                if (m < NOUT) sOut[n * 36 + m] = acc2[nt][mt][r] + sB2[m];
            }
    }
    __syncthreads();

    float* og = out + pbase * NOUT;
    for (int i = tid; i < MPTS * NOUT; i += 256) {
        int n = i / 33, m = i - 33 * n;
        og[i] = sOut[n * 36 + m];
    }
}

// ---------------------------------------------------------------------------
// Fallback: fully scalar, no workspace.
// ---------------------------------------------------------------------------
__global__ __launch_bounds__(256) void fused_fallback_k(const float* __restrict__ planes,
                                                        const float* __restrict__ points,
                                                        const float* __restrict__ W0,
                                                        const float* __restrict__ b0,
                                                        const float* __restrict__ W1,
                                                        const float* __restrict__ b1,
                                                        const float* __restrict__ W2,
                                                        const float* __restrict__ b2,
                                                        float* __restrict__ out) {
    const int tid = threadIdx.x;
    const int pgl = blockIdx.x * 256 + tid;
    const int b = pgl >> 19;
    const float px = points[(size_t)pgl * 3 + 0];
    const float py = points[(size_t)pgl * 3 + 1];
    const float pz = points[(size_t)pgl * 3 + 2];
    float feat[CP];
#pragma unroll
    for (int c = 0; c < CP; ++c) feat[c] = 0.f;
#pragma unroll
    for (int p = 0; p < PLANES; ++p) {
        const float gx = (p == 2) ? py : px;
        const float gy = (p == 0) ? py : pz;
        const float x = (gx + 1.0f) * 128.0f - 0.5f;
        const float y = (gy + 1.0f) * 128.0f - 0.5f;
        const float xf = floorf(x), yf = floorf(y);
        const float wx = x - xf, wy = y - yf;
        const int ix0 = (int)xf, iy0 = (int)yf;
        const float* pb = planes + (((size_t)(b * 96 + p * 32)) << 16);
        auto corner = [&](int ix, int iy, float w) {
            const bool v = (ix >= 0) & (ix < WW) & (iy >= 0) & (iy < HH);
            w = v ? w : 0.f;
            const int ixc = min(max(ix, 0), WW - 1);
            const int iyc = min(max(iy, 0), HH - 1);
            const int yx = (iyc << 8) | ixc;
            const float* src = pb + yx;
#pragma unroll
            for (int c = 0; c < CP; ++c) feat[c] = fmaf(w, src[(size_t)c << 16], feat[c]);
        };
        corner(ix0,     iy0,     (1.f - wx) * (1.f - wy));
        corner(ix0 + 1, iy0,     wx * (1.f - wy));
        corner(ix0,     iy0 + 1, (1.f - wx) * wy);
        corner(ix0 + 1, iy0 + 1, wx * wy);
    }
    float h0[HID];
#pragma unroll
    for (int j = 0; j < HID; ++j) h0[j] = b0[j];
    for (int k = 0; k < CP; ++k) {
        const float f = feat[k];
#pragma unroll
        for (int j = 0; j < HID; ++j) h0[j] = fmaf(f, W0[k * HID + j], h0[j]);
    }
#pragma unroll
    for (int j = 0; j < HID; ++j) h0[j] = (h0[j] >= 0.f) ? h0[j] : 0.01f * h0[j];
    float h1[HID];
#pragma unroll
    for (int j = 0; j < HID; ++j) h1[j] = b1[j];
    for (int k = 0; k < HID; ++k) {
        const float f = h0[k];
#pragma unroll
        for (int j = 0; j < HID; ++j) h1[j] = fmaf(f, W1[k * HID + j], h1[j]);
    }
#pragma unroll
    for (int j = 0; j < HID; ++j) h1[j] = (h1[j] >= 0.f) ? h1[j] : 0.01f * h1[j];
    float o[NOUT];
#pragma unroll
    for (int j = 0; j < NOUT; ++j) o[j] = b2[j];
    for (int k = 0; k < HID; ++k) {
        const float f = h1[k];
#pragma unroll
        for (int j = 0; j < NOUT; ++j) o[j] = fmaf(f, W2[k * NOUT + j], o[j]);
    }
    float* op = out + (size_t)pgl * NOUT;
#pragma unroll
    for (int j = 0; j < NOUT; ++j) op[j] = o[j];
}

// ---------------------------------------------------------------------------
extern "C" void kernel_launch(void* const* d_in, const int* in_sizes, int n_in,
                              void* d_out, int out_size, void* d_ws, size_t ws_size,
                              hipStream_t stream) {
    const float* triplane = (const float*)d_in[0];
    const float* points   = (const float*)d_in[1];
    const float* W0 = (const float*)d_in[2];
    const float* b0 = (const float*)d_in[3];
    const float* W1 = (const float*)d_in[4];
    const float* b1 = (const float*)d_in[5];
    const float* W2 = (const float*)d_in[6];
    const float* b2 = (const float*)d_in[7];
    float* out = (float*)d_out;

    const size_t dupElems = (size_t)BATCH * PLANES * PLANE_ELEMS_DUP;
    const size_t needDup  = dupElems * sizeof(u16);                    // 50.3 MB
    const size_t needAll  = needDup + GW_ELEMS * sizeof(u16);          // + 18.4 KB

    if (d_ws != nullptr && ws_size >= needAll) {
        u16* planesW = (u16*)d_ws;
        u16* gW      = planesW + dupElems;
        transpose_dup_k<<<(BATCH * PLANES * HWSZ) / 256, 256, 0, stream>>>(triplane, planesW);
        prep_w_k<<<GW_ELEMS / 256, 256, 0, stream>>>(W0, W1, W2, gW);
        fused6_k<<<NPTS_TOTAL / MPTS, 256, 0, stream>>>(planesW, gW, points, b0, b1, b2, out);
    } else if (d_ws != nullptr && ws_size >= needDup) {
        u16* planesW = (u16*)d_ws;
        transpose_dup_k<<<(BATCH * PLANES * HWSZ) / 256, 256, 0, stream>>>(triplane, planesW);
        fused_mfma_k<<<NPTS_TOTAL / MPTS, 256, 0, stream>>>(planesW, points, W0, b0, W1, b1, W2, b2, out);
    } else {
        fused_fallback_k<<<NPTS_TOTAL / 256, 256, 0, stream>>>(
            triplane, points, W0, b0, W1, b1, W2, b2, out);
    }
}

// Round 7
// 364.011 us; speedup vs baseline: 1.0653x; 1.0052x over previous
//
#include <hip/hip_runtime.h>

// Problem constants
#define BATCH 2
#define PLANES 3
#define CP 32
#define HH 256
#define WW 256
#define HWSZ 65536
#define HID 64
#define NOUT 33
#define NPTS_TOTAL 1048576
#define PLANE_ELEMS 2097152      // HWSZ*CP (u16 elems per plane, non-dup layout)
#define PLANE_ELEMS_DUP 4194304  // HWSZ*CP*2 (u16 elems per plane, dup-pair layout)
#define MPTS 128                 // points per fused block
#define GW_ELEMS 9216            // 2048 (W0t) + 4096 (W1t) + 3072 (W2t) bf16

typedef unsigned int u32;
typedef unsigned short u16;
typedef float floatx4 __attribute__((ext_vector_type(4)));
typedef short bf16x8 __attribute__((ext_vector_type(8)));

static __device__ __forceinline__ u16 f2bf(float f) {
    u32 u = __float_as_uint(f);
    return (u16)((u + 0x7fffu + ((u >> 16) & 1u)) >> 16);  // RNE
}
static __device__ __forceinline__ float bflo(u32 u) { return __uint_as_float(u << 16); }
static __device__ __forceinline__ float bfhi(u32 u) { return __uint_as_float(u & 0xffff0000u); }

// ---------------------------------------------------------------------------
// Kernel 1: transpose triplane (B,96,H,W) fp32 -> dup-pair layout
// (B*3, H, W, 32ch, 2) bf16: each 128-B pixel-block holds (v[x], v[x+1]) per
// channel -> any bilinear x-pair is ONE fully-utilized cache line.
// Block x=255 bakes in v1=0 (x+1 OOB).
// ---------------------------------------------------------------------------
__global__ __launch_bounds__(256) void transpose_dup_k(const float* __restrict__ tp,
                                                       u16* __restrict__ out) {
    int idx = blockIdx.x * 256 + threadIdx.x;  // < 6*65536
    int bp = idx >> 16;
    int yx = idx & 65535;
    int x = yx & 255;
    int b = bp / 3, p = bp - 3 * b;
    const float* src = tp + (((size_t)(b * 96 + p * 32)) << 16) + yx;
    const bool hasx1 = (x < 255);
    u16 v0[32], v1[32];
#pragma unroll
    for (int c = 0; c < 32; ++c) {
        v0[c] = f2bf(src[(size_t)c << 16]);
        v1[c] = hasx1 ? f2bf(src[((size_t)c << 16) + 1]) : (u16)0;
    }
    uint4* dst = (uint4*)(out + ((size_t)idx << 6));  // 64 u16 = 128 B per block
#pragma unroll
    for (int i = 0; i < 8; ++i) {
        uint4 w;
        w.x = (u32)v0[4 * i + 0] | ((u32)v1[4 * i + 0] << 16);
        w.y = (u32)v0[4 * i + 1] | ((u32)v1[4 * i + 1] << 16);
        w.z = (u32)v0[4 * i + 2] | ((u32)v1[4 * i + 2] << 16);
        w.w = (u32)v0[4 * i + 3] | ((u32)v1[4 * i + 3] << 16);
        dst[i] = w;
    }
}

// ---------------------------------------------------------------------------
// Kernel 1b: pre-tile MLP weights into fragment-major bf16 blob (once).
// gW[0..2048)      = W0t[m][k] (m<64,k<32):  gW[m*32+k]        = W0[k*64+m]
// gW[2048..6144)   = W1t[m][k] (64x64):      gW[2048+m*64+k]   = W1[k*64+m]
// gW[6144..9216)   = W2t[m][k] (m<48,k<64):  gW[6144+m*64+k]   = W2[k*33+m] (m<33) else 0
// ---------------------------------------------------------------------------
__global__ __launch_bounds__(256) void prep_w_k(const float* __restrict__ W0,
                                                const float* __restrict__ W1,
                                                const float* __restrict__ W2,
                                                u16* __restrict__ gW) {
    int i = blockIdx.x * 256 + threadIdx.x;  // < GW_ELEMS
    if (i < 2048) {
        int m = i >> 5, k = i & 31;
        gW[i] = f2bf(W0[k * 64 + m]);
    } else if (i < 6144) {
        int j = i - 2048;
        int m = j >> 6, k = j & 63;
        gW[i] = f2bf(W1[k * 64 + m]);
    } else {
        int j = i - 6144;
        int m = j >> 6, k = j & 63;
        gW[i] = (m < NOUT) ? f2bf(W2[k * NOUT + m]) : (u16)0;
    }
}

// ---------------------------------------------------------------------------
// Kernel 2: fused gather + MFMA MLP, v6 -- BARRIER-FREE.
// Key insight: every LDS row n = wv*32+it*16+ln is written AND read only by
// wave wv (weights live in global gW; X0 is a register handoff).  All
// __syncthreads() were pure lockstep overhead -> removed.  Each wave streams
// gather -> L0 -> L1 -> L2 -> store independently; in-wave LDS RAW ordering
// is enforced by compiler-inserted lgkmcnt.  Final copy is wave-local (wave
// wv copies its own 32 points, 256-B coalesced per instruction).
// No launch_bounds wave hint: prior rounds suggest the 2nd arg acts as a
// wave cap (53%@4, 63%@6, 84%@8); natural allocation (44 VGPR @ budget 128)
// did not spill, so let the HW run as many waves as resources allow.
// LDS: single sX (128*72 u16 = 18.4 KB) time-shared X1 -> X2 -> sOut.
// MFMA semantics (verified): D[m][n] = sum_k Wt[m][k]*X[n][k],
// A[m=lane&15][k=qd*8+j], B[k=qd*8+j][n=lane&15], D: col=lane&15(n),
// row=qd*4+r(m). Padded LDS stride 72 keeps b128 reads conflict-free.
// ---------------------------------------------------------------------------
__global__ __launch_bounds__(256) void fused7_k(const u16* __restrict__ planes,
                                                const u16* __restrict__ gW,
                                                const float* __restrict__ points,
                                                const float* __restrict__ b0,
                                                const float* __restrict__ b1,
                                                const float* __restrict__ b2,
                                                float* __restrict__ out) {
    __shared__ __align__(16) u16 sX[MPTS * 72];   // X1, then X2, then sOut (f32 stride 36)

    const int tid = threadIdx.x;
    const int lane = tid & 63, wv = tid >> 6;
    const int ln = lane & 15, qd = lane >> 4;
    const size_t pbase = (size_t)blockIdx.x * MPTS;
    const int bBatch = blockIdx.x >> 12;  // 4096 blocks per batch

    // ---- gather phase: produce layer-0 B-fragments directly in registers ----
    bf16x8 bfr[2];
#pragma unroll
    for (int it = 0; it < 2; ++it) {
        const int pt = wv * 32 + it * 16 + ln;
        const size_t gpt = pbase + pt;
        const float px = points[gpt * 3 + 0];
        const float py = points[gpt * 3 + 1];
        const float pz = points[gpt * 3 + 2];
        float acc[8];
#pragma unroll
        for (int j = 0; j < 8; ++j) acc[j] = 0.f;
#pragma unroll
        for (int p = 0; p < PLANES; ++p) {
            const float gx = (p == 2) ? py : px;
            const float gy = (p == 0) ? py : pz;
            const float x = (gx + 1.0f) * 128.0f - 0.5f;
            const float y = (gy + 1.0f) * 128.0f - 0.5f;
            const float xf = floorf(x), yf = floorf(y);
            const float wx = x - xf, wy = y - yf;
            const int ix0 = (int)xf, iy0 = (int)yf;          // in [-1,255]
            const int xb = max(ix0, 0);
            const float wA0 = (ix0 >= 0) ? (1.f - wx) : wx;  // x0=-1: wx*v[0] via lo half
            const float wB0 = (ix0 >= 0) ? wx : 0.f;
            const u16* pb = planes + ((size_t)(bBatch * 3 + p) << 22);
#pragma unroll
            for (int r = 0; r < 2; ++r) {
                const int iy = iy0 + r;
                const bool vy = (iy >= 0) & (iy < HH);
                const float wrow = (r ? wy : (1.f - wy));
                const float wa = vy ? wrow * wA0 : 0.f;
                const float wb = vy ? wrow * wB0 : 0.f;
                const int iyc = min(max(iy, 0), HH - 1);
                const u16* src = pb + (((size_t)((iyc << 8) | xb)) << 6) + (qd << 4);
                const uint4 d0 = *(const uint4*)src;        // ch qd*8+0..3 (lo/hi = x0/x1)
                const uint4 d1 = *(const uint4*)(src + 8);  // ch qd*8+4..7
#pragma unroll
                for (int j = 0; j < 4; ++j) {
                    const u32 u = (&d0.x)[j];
                    acc[j] = fmaf(wa, bflo(u), fmaf(wb, bfhi(u), acc[j]));
                    const u32 u2 = (&d1.x)[j];
                    acc[4 + j] = fmaf(wa, bflo(u2), fmaf(wb, bfhi(u2), acc[4 + j]));
                }
            }
        }
        u32 w[4];
#pragma unroll
        for (int j = 0; j < 4; ++j)
            w[j] = (u32)f2bf(acc[2 * j]) | ((u32)f2bf(acc[2 * j + 1]) << 16);
        bf16x8 v;
        ((u32*)&v)[0] = w[0]; ((u32*)&v)[1] = w[1];
        ((u32*)&v)[2] = w[2]; ((u32*)&v)[3] = w[3];
        bfr[it] = v;
    }

    // ---- layer 0: K=32, M=64 (4 tiles); per-mt interleaved epilogue ----
    {
#pragma unroll
        for (int mt = 0; mt < 4; ++mt) {
            const bf16x8 a0 = *(const bf16x8*)(gW + (mt * 16 + ln) * 32 + qd * 8);
            const float4 bias0 = *(const float4*)(b0 + mt * 16 + qd * 4);
#pragma unroll
            for (int it = 0; it < 2; ++it) {
                floatx4 z = {0.f, 0.f, 0.f, 0.f};
                floatx4 acc = __builtin_amdgcn_mfma_f32_16x16x32_bf16(a0, bfr[it], z, 0, 0, 0);
                const int n = wv * 32 + it * 16 + ln;
                u16 p[4];
#pragma unroll
                for (int r = 0; r < 4; ++r) {
                    float v = acc[r] + (&bias0.x)[r];
                    v = (v >= 0.f) ? v : 0.01f * v;
                    p[r] = f2bf(v);
                }
                uint2 dd = make_uint2((u32)p[0] | ((u32)p[1] << 16), (u32)p[2] | ((u32)p[3] << 16));
                *(uint2*)(sX + n * 72 + mt * 16 + qd * 4) = dd;
            }
        }
    }
    // (no barrier: X1 rows are wave-private)

    // ---- layer 1: K=64 (2 chunks); upfront weight frags; pack early ----
    uint2 pk1[2][4];
    {
        const u16* gW1 = gW + 2048;
        bf16x8 a1[4][2];
#pragma unroll
        for (int mt = 0; mt < 4; ++mt)
#pragma unroll
            for (int c = 0; c < 2; ++c)
                a1[mt][c] = *(const bf16x8*)(gW1 + (mt * 16 + ln) * 64 + c * 32 + qd * 8);
#pragma unroll
        for (int it = 0; it < 2; ++it) {
            const int n = wv * 32 + it * 16 + ln;
            const bf16x8 f0 = *(const bf16x8*)(sX + n * 72 + qd * 8);
            const bf16x8 f1 = *(const bf16x8*)(sX + n * 72 + 32 + qd * 8);
#pragma unroll
            for (int mt = 0; mt < 4; ++mt) {
                floatx4 z = {0.f, 0.f, 0.f, 0.f};
                floatx4 t = __builtin_amdgcn_mfma_f32_16x16x32_bf16(a1[mt][0], f0, z, 0, 0, 0);
                floatx4 acc = __builtin_amdgcn_mfma_f32_16x16x32_bf16(a1[mt][1], f1, t, 0, 0, 0);
                const float4 bias1 = *(const float4*)(b1 + mt * 16 + qd * 4);
                u16 p[4];
#pragma unroll
                for (int r = 0; r < 4; ++r) {
                    float v = acc[r] + (&bias1.x)[r];
                    v = (v >= 0.f) ? v : 0.01f * v;
                    p[r] = f2bf(v);
                }
                pk1[it][mt] = make_uint2((u32)p[0] | ((u32)p[1] << 16), (u32)p[2] | ((u32)p[3] << 16));
            }
        }
    }
    // (no barrier: X1 reads and X2 writes below touch only this wave's rows)

    // write X2 (stride 72)
#pragma unroll
    for (int it = 0; it < 2; ++it) {
        const int n = wv * 32 + it * 16 + ln;
#pragma unroll
        for (int mt = 0; mt < 4; ++mt)
            *(uint2*)(sX + n * 72 + mt * 16 + qd * 4) = pk1[it][mt];
    }
    // (no barrier)

    // ---- layer 2: K=64, M=48 (3 tiles; m<33 valid); upfront weight frags ----
    floatx4 acc2[2][3];
    {
        const u16* gW2 = gW + 6144;
        bf16x8 a2[3][2];
#pragma unroll
        for (int mt = 0; mt < 3; ++mt)
#pragma unroll
            for (int c = 0; c < 2; ++c)
                a2[mt][c] = *(const bf16x8*)(gW2 + (mt * 16 + ln) * 64 + c * 32 + qd * 8);
#pragma unroll
        for (int it = 0; it < 2; ++it) {
            const int n = wv * 32 + it * 16 + ln;
            const bf16x8 f0 = *(const bf16x8*)(sX + n * 72 + qd * 8);
            const bf16x8 f1 = *(const bf16x8*)(sX + n * 72 + 32 + qd * 8);
#pragma unroll
            for (int mt = 0; mt < 3; ++mt) {
                floatx4 z = {0.f, 0.f, 0.f, 0.f};
                floatx4 t = __builtin_amdgcn_mfma_f32_16x16x32_bf16(a2[mt][0], f0, z, 0, 0, 0);
                acc2[it][mt] = __builtin_amdgcn_mfma_f32_16x16x32_bf16(a2[mt][1], f1, t, 0, 0, 0);
            }
        }
    }
    // (no barrier)

    // epilogue 2 -> sOut fp32 stride 36 (overlays this wave's own X rows:
    // sOut row n bytes = n*144 == sX row n bytes)
    float* sOut = (float*)sX;
#pragma unroll
    for (int it = 0; it < 2; ++it) {
        const int n = wv * 32 + it * 16 + ln;
#pragma unroll
        for (int mt = 0; mt < 3; ++mt)
#pragma unroll
            for (int r = 0; r < 4; ++r) {
                const int m = mt * 16 + qd * 4 + r;
                if (m < NOUT) sOut[n * 36 + m] = acc2[it][mt][r] + b2[m];
            }
    }
    // (no barrier)

    // wave-local coalesced copy out: wave wv copies its own 32 points
    {
        const int nbase = wv * 32;
        float* og = out + (pbase + nbase) * NOUT;
        for (int i = lane; i < 32 * NOUT; i += 64) {
            int n = i / 33, m = i - 33 * n;
            og[i] = sOut[(nbase + n) * 36 + m];
        }
    }
}

// ---------------------------------------------------------------------------
// Fallback: round-1 fused kernel (ws >= dup planes only). 210 us measured.
// ---------------------------------------------------------------------------
__global__ __launch_bounds__(256, 2) void fused_mfma_k(const u16* __restrict__ planes,
                                                       const float* __restrict__ points,
                                                       const float* __restrict__ W0,
                                                       const float* __restrict__ b0,
                                                       const float* __restrict__ W1,
                                                       const float* __restrict__ b1,
                                                       const float* __restrict__ W2,
                                                       const float* __restrict__ b2,
                                                       float* __restrict__ out) {
    __shared__ __align__(16) u16 sW0t[64 * 40];
    __shared__ __align__(16) u16 sW1t[64 * 72];
    __shared__ __align__(16) u16 sW2t[48 * 72];
    __shared__ __align__(16) u16 sR0[MPTS * 72];
    __shared__ __align__(16) u16 sR1[MPTS * 72];
    __shared__ float sB0[64], sB1[64], sB2[33];

    const int tid = threadIdx.x;
    for (int i = tid; i < 32 * 64; i += 256) { int k = i >> 6, m = i & 63; sW0t[m * 40 + k] = f2bf(W0[i]); }
    for (int i = tid; i < 64 * 64; i += 256) { int k = i >> 6, m = i & 63; sW1t[m * 72 + k] = f2bf(W1[i]); }
    for (int i = tid; i < 64 * 33; i += 256) { int k = i / 33, m = i - 33 * k; sW2t[m * 72 + k] = f2bf(W2[i]); }
    if (tid < 64) { sB0[tid] = b0[tid]; sB1[tid] = b1[tid]; }
    if (tid < 33) sB2[tid] = b2[tid];

    const size_t pbase = (size_t)blockIdx.x * MPTS;
    float* sPts = (float*)sR1;  // overlay; dead before epilogue 0
    for (int i = tid; i < MPTS * 3; i += 256) sPts[i] = points[pbase * 3 + i];
    __syncthreads();

    const int bBatch = blockIdx.x >> 12;
#pragma unroll
    for (int t = 0; t < 2; ++t) {
        const int task = t * 256 + tid;
        const int pt = task >> 2, q = task & 3;
        const float px = sPts[pt * 3 + 0];
        const float py = sPts[pt * 3 + 1];
        const float pz = sPts[pt * 3 + 2];
        float acc[8];
#pragma unroll
        for (int j = 0; j < 8; ++j) acc[j] = 0.f;
#pragma unroll
        for (int p = 0; p < PLANES; ++p) {
            const float gx = (p == 2) ? py : px;
            const float gy = (p == 0) ? py : pz;
            const float x = (gx + 1.0f) * 128.0f - 0.5f;
            const float y = (gy + 1.0f) * 128.0f - 0.5f;
            const float xf = floorf(x), yf = floorf(y);
            const float wx = x - xf, wy = y - yf;
            const int ix0 = (int)xf, iy0 = (int)yf;
            const int xb = max(ix0, 0);
            const float ax = (ix0 >= 0) ? (1.f - wx) : wx;
            const float bx = (ix0 >= 0) ? wx : 0.f;
            const u16* pb = planes + ((size_t)(bBatch * 3 + p) << 22);
#pragma unroll
            for (int r = 0; r < 2; ++r) {
                const int iy = iy0 + r;
                const bool vy = (iy >= 0) & (iy < HH);
                const float wrow = (r ? wy : (1.f - wy));
                const float wa = vy ? wrow * ax : 0.f;
                const float wb = vy ? wrow * bx : 0.f;
                const int iyc = min(max(iy, 0), HH - 1);
                const u16* src = pb + (((size_t)((iyc << 8) | xb)) << 6) + (q << 4);
                const uint4 d0 = *(const uint4*)src;
                const uint4 d1 = *(const uint4*)(src + 8);
#pragma unroll
                for (int j = 0; j < 4; ++j) {
                    const u32 u = (&d0.x)[j];
                    acc[j] = fmaf(wa, bflo(u), fmaf(wb, bfhi(u), acc[j]));
                    const u32 u2 = (&d1.x)[j];
                    acc[4 + j] = fmaf(wa, bflo(u2), fmaf(wb, bfhi(u2), acc[4 + j]));
                }
            }
        }
        uint4 o;
        o.x = (u32)f2bf(acc[0]) | ((u32)f2bf(acc[1]) << 16);
        o.y = (u32)f2bf(acc[2]) | ((u32)f2bf(acc[3]) << 16);
        o.z = (u32)f2bf(acc[4]) | ((u32)f2bf(acc[5]) << 16);
        o.w = (u32)f2bf(acc[6]) | ((u32)f2bf(acc[7]) << 16);
        *(uint4*)(sR0 + pt * 40 + q * 8) = o;
    }
    __syncthreads();

    const int lane = tid & 63, wv = tid >> 6;
    const int ln = lane & 15, qd = lane >> 4;

    bf16x8 a0[4];
#pragma unroll
    for (int mt = 0; mt < 4; ++mt)
        a0[mt] = *(const bf16x8*)(sW0t + (mt * 16 + ln) * 40 + qd * 8);
    bf16x8 bx0[2];
#pragma unroll
    for (int nt = 0; nt < 2; ++nt)
        bx0[nt] = *(const bf16x8*)(sR0 + (wv * 32 + nt * 16 + ln) * 40 + qd * 8);
    floatx4 acc0[2][4];
#pragma unroll
    for (int nt = 0; nt < 2; ++nt)
#pragma unroll
        for (int mt = 0; mt < 4; ++mt) {
            floatx4 z = {0.f, 0.f, 0.f, 0.f};
            acc0[nt][mt] = __builtin_amdgcn_mfma_f32_16x16x32_bf16(a0[mt], bx0[nt], z, 0, 0, 0);
        }
#pragma unroll
    for (int nt = 0; nt < 2; ++nt) {
        const int n = wv * 32 + nt * 16 + ln;
#pragma unroll
        for (int mt = 0; mt < 4; ++mt) {
            u16 p[4];
#pragma unroll
            for (int r = 0; r < 4; ++r) {
                const int m = mt * 16 + qd * 4 + r;
                float v = acc0[nt][mt][r] + sB0[m];
                v = (v >= 0.f) ? v : 0.01f * v;
                p[r] = f2bf(v);
            }
            uint2 dd = make_uint2((u32)p[0] | ((u32)p[1] << 16), (u32)p[2] | ((u32)p[3] << 16));
            *(uint2*)(sR1 + n * 72 + mt * 16 + qd * 4) = dd;
        }
    }

    bf16x8 a1[4][2];
#pragma unroll
    for (int mt = 0; mt < 4; ++mt)
#pragma unroll
        for (int c = 0; c < 2; ++c)
            a1[mt][c] = *(const bf16x8*)(sW1t + (mt * 16 + ln) * 72 + c * 32 + qd * 8);
    floatx4 acc1[2][4];
#pragma unroll
    for (int nt = 0; nt < 2; ++nt) {
        const int n = wv * 32 + nt * 16 + ln;
        bf16x8 bf0 = *(const bf16x8*)(sR1 + n * 72 + qd * 8);
        bf16x8 bf1 = *(const bf16x8*)(sR1 + n * 72 + 32 + qd * 8);
#pragma unroll
        for (int mt = 0; mt < 4; ++mt) {
            floatx4 z = {0.f, 0.f, 0.f, 0.f};
            floatx4 t = __builtin_amdgcn_mfma_f32_16x16x32_bf16(a1[mt][0], bf0, z, 0, 0, 0);
            acc1[nt][mt] = __builtin_amdgcn_mfma_f32_16x16x32_bf16(a1[mt][1], bf1, t, 0, 0, 0);
        }
    }
    __syncthreads();

#pragma unroll
    for (int nt = 0; nt < 2; ++nt) {
        const int n = wv * 32 + nt * 16 + ln;
#pragma unroll
        for (int mt = 0; mt < 4; ++mt) {
            u16 p[4];
#pragma unroll
            for (int r = 0; r < 4; ++r) {
                const int m = mt * 16 + qd * 4 + r;
                float v = acc1[nt][mt][r] + sB1[m];
                v = (v >= 0.f) ? v : 0.01f * v;
                p[r] = f2bf(v);
            }
            uint2 dd = make_uint2((u32)p[0] | ((u32)p[1] << 16), (u32)p[2] | ((u32)p[3] << 16));
            *(uint2*)(sR0 + n * 72 + mt * 16 + qd * 4) = dd;
        }
    }

    bf16x8 a2[3][2];
#pragma unroll
    for (int mt = 0; mt < 3; ++mt)
#pragma unroll
        for (int c = 0; c < 2; ++c)
            a2[mt][c] = *(const bf16x8*)(sW2t + (mt * 16 + ln) * 72 + c * 32 + qd * 8);
    floatx4 acc2[2][3];
#pragma unroll
    for (int nt = 0; nt < 2; ++nt) {
        const int n = wv * 32 + nt * 16 + ln;
        bf16x8 bf0 = *(const bf16x8*)(sR0 + n * 72 + qd * 8);
        bf16x8 bf1 = *(const bf16x8*)(sR0 + n * 72 + 32 + qd * 8);
#pragma unroll
        for (int mt = 0; mt < 3; ++mt) {
            floatx4 z = {0.f, 0.f, 0.f, 0.f};
            floatx4 t = __builtin_amdgcn_mfma_f32_16x16x32_bf16(a2[mt][0], bf0, z, 0, 0, 0);
            acc2[nt][mt] = __builtin_amdgcn_mfma_f32_16x16x32_bf16(a2[mt][1], bf1, t, 0, 0, 0);
        }
    }
    __syncthreads();

    float* sOut = (float*)sR1;
#pragma unroll
    for (int nt = 0; nt < 2; ++nt) {
        const int n = wv * 32 + nt * 16 + ln;
#pragma unroll
        for (int mt = 0; mt < 3; ++mt)
#pragma unroll
            for (int r = 0; r < 4; ++r) {
                const int m = mt * 16 + qd * 4 + r;
                if (m < NOUT) sOut[n * 36 + m] = acc2[nt][mt][r] + sB2[m];
            }
    }
    __syncthreads();

    float* og = out + pbase * NOUT;
    for (int i = tid; i < MPTS * NOUT; i += 256) {
        int n = i / 33, m = i - 33 * n;
        og[i] = sOut[n * 36 + m];
    }
}

// ---------------------------------------------------------------------------
// Fallback: fully scalar, no workspace.
// ---------------------------------------------------------------------------
__global__ __launch_bounds__(256) void fused_fallback_k(const float* __restrict__ planes,
                                                        const float* __restrict__ points,
                                                        const float* __restrict__ W0,
                                                        const float* __restrict__ b0,
                                                        const float* __restrict__ W1,
                                                        const float* __restrict__ b1,
                                                        const float* __restrict__ W2,
                                                        const float* __restrict__ b2,
                                                        float* __restrict__ out) {
    const int tid = threadIdx.x;
    const int pgl = blockIdx.x * 256 + tid;
    const int b = pgl >> 19;
    const float px = points[(size_t)pgl * 3 + 0];
    const float py = points[(size_t)pgl * 3 + 1];
    const float pz = points[(size_t)pgl * 3 + 2];
    float feat[CP];
#pragma unroll
    for (int c = 0; c < CP; ++c) feat[c] = 0.f;
#pragma unroll
    for (int p = 0; p < PLANES; ++p) {
        const float gx = (p == 2) ? py : px;
        const float gy = (p == 0) ? py : pz;
        const float x = (gx + 1.0f) * 128.0f - 0.5f;
        const float y = (gy + 1.0f) * 128.0f - 0.5f;
        const float xf = floorf(x), yf = floorf(y);
        const float wx = x - xf, wy = y - yf;
        const int ix0 = (int)xf, iy0 = (int)yf;
        const float* pb = planes + (((size_t)(b * 96 + p * 32)) << 16);
        auto corner = [&](int ix, int iy, float w) {
            const bool v = (ix >= 0) & (ix < WW) & (iy >= 0) & (iy < HH);
            w = v ? w : 0.f;
            const int ixc = min(max(ix, 0), WW - 1);
            const int iyc = min(max(iy, 0), HH - 1);
            const int yx = (iyc << 8) | ixc;
            const float* src = pb + yx;
#pragma unroll
            for (int c = 0; c < CP; ++c) feat[c] = fmaf(w, src[(size_t)c << 16], feat[c]);
        };
        corner(ix0,     iy0,     (1.f - wx) * (1.f - wy));
        corner(ix0 + 1, iy0,     wx * (1.f - wy));
        corner(ix0,     iy0 + 1, (1.f - wx) * wy);
        corner(ix0 + 1, iy0 + 1, wx * wy);
    }
    float h0[HID];
#pragma unroll
    for (int j = 0; j < HID; ++j) h0[j] = b0[j];
    for (int k = 0; k < CP; ++k) {
        const float f = feat[k];
#pragma unroll
        for (int j = 0; j < HID; ++j) h0[j] = fmaf(f, W0[k * HID + j], h0[j]);
    }
#pragma unroll
    for (int j = 0; j < HID; ++j) h0[j] = (h0[j] >= 0.f) ? h0[j] : 0.01f * h0[j];
    float h1[HID];
#pragma unroll
    for (int j = 0; j < HID; ++j) h1[j] = b1[j];
    for (int k = 0; k < HID; ++k) {
        const float f = h0[k];
#pragma unroll
        for (int j = 0; j < HID; ++j) h1[j] = fmaf(f, W1[k * HID + j], h1[j]);
    }
#pragma unroll
    for (int j = 0; j < HID; ++j) h1[j] = (h1[j] >= 0.f) ? h1[j] : 0.01f * h1[j];
    float o[NOUT];
#pragma unroll
    for (int j = 0; j < NOUT; ++j) o[j] = b2[j];
    for (int k = 0; k < HID; ++k) {
        const float f = h1[k];
#pragma unroll
        for (int j = 0; j < NOUT; ++j) o[j] = fmaf(f, W2[k * NOUT + j], o[j]);
    }
    float* op = out + (size_t)pgl * NOUT;
#pragma unroll
    for (int j = 0; j < NOUT; ++j) op[j] = o[j];
}

// ---------------------------------------------------------------------------
extern "C" void kernel_launch(void* const* d_in, const int* in_sizes, int n_in,
                              void* d_out, int out_size, void* d_ws, size_t ws_size,
                              hipStream_t stream) {
    const float* triplane = (const float*)d_in[0];
    const float* points   = (const float*)d_in[1];
    const float* W0 = (const float*)d_in[2];
    const float* b0 = (const float*)d_in[3];
    const float* W1 = (const float*)d_in[4];
    const float* b1 = (const float*)d_in[5];
    const float* W2 = (const float*)d_in[6];
    const float* b2 = (const float*)d_in[7];
    float* out = (float*)d_out;

    const size_t dupElems = (size_t)BATCH * PLANES * PLANE_ELEMS_DUP;
    const size_t needDup  = dupElems * sizeof(u16);                    // 50.3 MB
    const size_t needAll  = needDup + GW_ELEMS * sizeof(u16);          // + 18.4 KB

    if (d_ws != nullptr && ws_size >= needAll) {
        u16* planesW = (u16*)d_ws;
        u16* gW      = planesW + dupElems;
        transpose_dup_k<<<(BATCH * PLANES * HWSZ) / 256, 256, 0, stream>>>(triplane, planesW);
        prep_w_k<<<GW_ELEMS / 256, 256, 0, stream>>>(W0, W1, W2, gW);
        fused7_k<<<NPTS_TOTAL / MPTS, 256, 0, stream>>>(planesW, gW, points, b0, b1, b2, out);
    } else if (d_ws != nullptr && ws_size >= needDup) {
        u16* planesW = (u16*)d_ws;
        transpose_dup_k<<<(BATCH * PLANES * HWSZ) / 256, 256, 0, stream>>>(triplane, planesW);
        fused_mfma_k<<<NPTS_TOTAL / MPTS, 256, 0, stream>>>(planesW, points, W0, b0, W1, b1, W2, b2, out);
    } else {
        fused_fallback_k<<<NPTS_TOTAL / 256, 256, 0, stream>>>(
            triplane, points, W0, b0, W1, b1, W2, b2, out);
    }
}